// Round 6
// baseline (451.398 us; speedup 1.0000x reference)
//
#include <hip/hip_runtime.h>
#include <hip/hip_bf16.h>
#include <math.h>

// TransformerBlock B=4,S=1024,D=1024,H=16,DK=64,DFF=4096. Externals f32, out f32.
// GEMMs: wconv (f32 W -> Wt[N][K] bf16). Two GEMM engines:
//  - gemm_bt: 2-phase double-buffered 64x128/128x128 (proj/FF2/out, m-fast grid).
//  - gemm8_bt: 8-phase 256x256 (FF1, QKV): 512 thr / 8 waves (2m x 4n), BK=64,
//    128KB LDS dbuf, half-tile staging {A0,B0,B1,A1} issued BEFORE counted
//    vmcnt(6) (tail drains 4->2->0), 1 barrier/phase, XOR chunk-swizzle on both
//    glds-source and ds_read (bank-conflict-free), setprio around MFMA clusters.
//    K-accumulation order identical to gemm_bt (bit-identical outputs).
// Attention: register flash, defer-max, LDS-staged K/V glds double-buffer.

constexpr int Bc = 4, Sc_ = 1024, Dc = 1024, Hc = 16, DKc = 64, DFFc = 4096;
constexpr int ROWS = Bc * Sc_;   // 4096
constexpr int BK = 32;

typedef short short8 __attribute__((ext_vector_type(8)));
typedef __bf16 bf16x8 __attribute__((ext_vector_type(8)));
typedef float float4v __attribute__((ext_vector_type(4)));
typedef uint uint2v __attribute__((ext_vector_type(2)));

__device__ __forceinline__ float bf2f(ushort u) {
    union { uint i; float f; } v; v.i = ((uint)u) << 16; return v.f;
}
__device__ __forceinline__ ushort f2bf(float f) {
    union { float f; uint i; } v; v.f = f;
    uint r = v.i + 0x7FFF + ((v.i >> 16) & 1);   // RNE
    return (ushort)(r >> 16);
}
__device__ __forceinline__ bf16x8 as_bf(short8 s) {
    union { short8 s; bf16x8 b; } u; u.s = s; return u.b;
}
__device__ __forceinline__ uint cvt_pk_bf16(float lo, float hi) {
    uint r;
    asm("v_cvt_pk_bf16_f32 %0, %1, %2" : "=v"(r) : "v"(lo), "v"(hi));
    return r;
}
__device__ __forceinline__ float exp2_hw(float x) {   // v_exp_f32: 2^x, ~1 ulp
    float r;
    asm("v_exp_f32 %0, %1" : "=v"(r) : "v"(x));
    return r;
}
__device__ __forceinline__ void async_copy16(void* lds, const void* g) {
    __builtin_amdgcn_global_load_lds((const __attribute__((address_space(1))) uint*)g,
                                     (__attribute__((address_space(3))) uint*)lds, 16, 0, 0);
}
// exact-GELU via Abramowitz-Stegun erf (max abs err 1.5e-7)
__device__ __forceinline__ float gelu_f(float v) {
    float z = v * 0.70710678118654752f;
    float az = fabsf(z);
    float t = 1.f / (1.f + 0.3275911f * az);
    float p = ((((1.061405429f * t - 1.453152027f) * t) + 1.421413741f) * t
               - 0.284496736f) * t + 0.254829592f;
    float y = 1.f - p * t * __expf(-az * az);
    float er = (z < 0.f) ? -y : y;
    return 0.5f * v * (1.f + er);
}

__global__ void sentinel_kernel(float* __restrict__ out, int n) {
    int i = blockIdx.x * 256 + threadIdx.x;
    if (i < n) out[i] = 100.0f;
}

// combined qkv bias
__global__ void bias3_kernel(const float* __restrict__ a, const float* __restrict__ b,
                             const float* __restrict__ c, float* __restrict__ o) {
    int i = blockIdx.x * 256 + threadIdx.x;
    if (i < 1024) o[i] = a[i];
    else if (i < 2048) o[i] = b[i - 1024];
    else if (i < 3072) o[i] = c[i - 2048];
}

// ---- transpose+convert: W[K][N] f32 -> Wt[N][K] bf16, 64x64 tiles ----
__global__ __launch_bounds__(256) void wconv_kernel(const float* __restrict__ W,
                                                    ushort* __restrict__ Wt,
                                                    int K, int N) {
    __shared__ float T[64][65];
    const int kt = blockIdx.y * 64, nt = blockIdx.x * 64;
    const int tid = threadIdx.x;
#pragma unroll
    for (int it = 0; it < 4; it++) {
        int r = it * 16 + (tid >> 4), c = (tid & 15) * 4;
        float4v v = *reinterpret_cast<const float4v*>(W + (size_t)(kt + r) * N + nt + c);
        T[r][c] = v[0]; T[r][c + 1] = v[1]; T[r][c + 2] = v[2]; T[r][c + 3] = v[3];
    }
    __syncthreads();
    int n = tid >> 2, kc = (tid & 3) * 16;
    short8 a, b;
#pragma unroll
    for (int q = 0; q < 8; q++) {
        a[q] = (short)f2bf(T[kc + q][n]);
        b[q] = (short)f2bf(T[kc + 8 + q][n]);
    }
    ushort* dst = Wt + (size_t)(nt + n) * K + kt + kc;
    *reinterpret_cast<short8*>(dst) = a;
    *reinterpret_cast<short8*>(dst + 8) = b;
}

// ---- V transpose: V[b,h,s,dk] bf16 -> Vt[b,h,dk,s] bf16 ----
__global__ __launch_bounds__(256) void vconv_kernel(const ushort* __restrict__ V,
                                                    ushort* __restrict__ Vt) {
    __shared__ ushort T[64][65];
    const int bh = blockIdx.y;
    const int s0 = blockIdx.x * 64;
    const int tid = threadIdx.x;
    const int r = tid >> 2, c = (tid & 3) * 16;
    const ushort* src = V + ((size_t)bh * Sc_ + s0 + r) * DKc + c;
    short8 a = *reinterpret_cast<const short8*>(src);
    short8 b = *reinterpret_cast<const short8*>(src + 8);
#pragma unroll
    for (int q = 0; q < 8; q++) { T[r][c + q] = (ushort)a[q]; T[r][c + 8 + q] = (ushort)b[q]; }
    __syncthreads();
    const int dk = tid >> 2, sc2 = (tid & 3) * 16;
    short8 o0, o1;
#pragma unroll
    for (int q = 0; q < 8; q++) { o0[q] = (short)T[sc2 + q][dk]; o1[q] = (short)T[sc2 + 8 + q][dk]; }
    ushort* dst = Vt + ((size_t)bh * DKc + dk) * Sc_ + s0 + sc2;
    *reinterpret_cast<short8*>(dst) = o0;
    *reinterpret_cast<short8*>(dst + 8) = o1;
}

// ---- LayerNorm: one block per row of D=1024 ----
template<bool IN_F32>
__global__ __launch_bounds__(256) void ln_kernel(const void* __restrict__ xin,
                                                 const float* __restrict__ g,
                                                 const float* __restrict__ be,
                                                 ushort* __restrict__ out) {
    int row = blockIdx.x;
    int tid = threadIdx.x;
    float v0[4], s = 0.f, ss = 0.f;
#pragma unroll
    for (int i = 0; i < 4; i++) {
        int c = tid + i * 256;
        float f = IN_F32 ? ((const float*)xin)[(size_t)row * Dc + c]
                         : bf2f(((const ushort*)xin)[(size_t)row * Dc + c]);
        v0[i] = f; s += f; ss += f * f;
    }
#pragma unroll
    for (int off = 32; off > 0; off >>= 1) {
        s += __shfl_down(s, off);
        ss += __shfl_down(ss, off);
    }
    __shared__ float red[8];
    __shared__ float stat[2];
    int wave = tid >> 6, lane = tid & 63;
    if (lane == 0) { red[wave] = s; red[wave + 4] = ss; }
    __syncthreads();
    if (tid == 0) {
        float a = 0.f, b = 0.f;
        for (int w = 0; w < 4; w++) { a += red[w]; b += red[w + 4]; }
        stat[0] = a; stat[1] = b;
    }
    __syncthreads();
    float mean = stat[0] * (1.f / Dc);
    float var  = stat[1] * (1.f / Dc) - mean * mean;
    float inv  = rsqrtf(var + 1e-5f);
#pragma unroll
    for (int i = 0; i < 4; i++) {
        int c = tid + i * 256;
        float nv = (v0[i] - mean) * inv * g[c] + be[c];
        out[(size_t)row * Dc + c] = f2bf(nv);
    }
}

// ---- bt-GEMM, 2-phase double-buffered (proj / FF2 / out) ----
template<int BM, int BN, typename OutT>
__global__ __launch_bounds__(256) void gemm_bt(
    const ushort* __restrict__ Ag, const ushort* __restrict__ Wt,
    const float* __restrict__ biasg,
    const float* __restrict__ res1f,
    const ushort* __restrict__ resi1, const ushort* __restrict__ resi2,
    OutT* __restrict__ outg,
    int M, int N, int K, int do_gelu, int mode) {
    constexpr int WN = BN / 64;            // waves along n
    constexpr int WM = 4 / WN;             // waves along m
    constexpr int MI = BM / (WM * 16);     // m-frags per wave
    constexpr int TSZ = (BM + BN) * BK;    // shorts per LDS buffer
    constexpr int TOT = (BM + BN) * 4;     // 16B chunks per buffer
    __shared__ ushort Tile[2 * TSZ];
    const int tid = threadIdx.x;
    const int wave = tid >> 6, lane = tid & 63;
    const int quad = lane >> 4, l16 = lane & 15;
    const int m0 = blockIdx.x * BM, n0 = blockIdx.y * BN;
    const int wm = (wave / WN) * (MI * 16), wn = (wave % WN) * 64;

    float4v acc[MI][4];
    const float4v zero = {0.f, 0.f, 0.f, 0.f};
#pragma unroll
    for (int i = 0; i < MI; i++)
#pragma unroll
        for (int j = 0; j < 4; j++) acc[i][j] = zero;

    auto stage = [&](int buf, int k0) {
#pragma unroll
        for (int it = 0; it < TOT / 256; it++) {
            int c = tid + it * 256;
            int row = c >> 2, kc = (c & 3) * 8;
            const ushort* src = (row < BM)
                ? Ag + (size_t)(m0 + row) * K + k0 + kc
                : Wt + (size_t)(n0 + row - BM) * K + k0 + kc;
            async_copy16(&Tile[buf * TSZ + c * 8], src);
        }
    };

    const int nit = K / BK;
    stage(0, 0);
    for (int i = 0; i < nit; i++) {
        int buf = i & 1;
        __builtin_amdgcn_sched_barrier(0);
        __builtin_amdgcn_s_waitcnt(0x0F70);   // vmcnt(0): my glds for buf done
        __builtin_amdgcn_s_barrier();         // all waves agree
        __builtin_amdgcn_sched_barrier(0);
        if (i + 1 < nit) stage(buf ^ 1, (i + 1) * BK);   // prefetch overlaps compute
        __builtin_amdgcn_sched_barrier(0);
        const ushort* Asb = &Tile[buf * TSZ];
        const ushort* Bsb = &Tile[buf * TSZ + BM * BK];
        short8 af[MI], bfr[4];
#pragma unroll
        for (int ii = 0; ii < MI; ii++)
            af[ii] = *reinterpret_cast<const short8*>(&Asb[(wm + ii * 16 + l16) * BK + quad * 8]);
#pragma unroll
        for (int j = 0; j < 4; j++)
            bfr[j] = *reinterpret_cast<const short8*>(&Bsb[(wn + j * 16 + l16) * BK + quad * 8]);
#pragma unroll
        for (int j = 0; j < 4; j++)
#pragma unroll
            for (int ii = 0; ii < MI; ii++)
                acc[ii][j] = __builtin_amdgcn_mfma_f32_16x16x32_bf16(as_bf(af[ii]), as_bf(bfr[j]), acc[ii][j], 0, 0, 0);
    }
    __builtin_amdgcn_s_barrier();

    // epilogue: C/D layout col=lane&15, row=quad*4+reg
#pragma unroll
    for (int j = 0; j < 4; j++) {
        int cg = n0 + wn + j * 16 + l16;
        float bv = biasg ? biasg[cg] : 0.f;
#pragma unroll
        for (int i = 0; i < MI; i++) {
#pragma unroll
            for (int r = 0; r < 4; r++) {
                int rg = m0 + wm + i * 16 + quad * 4 + r;
                float v = acc[i][j][r] + bv;
                if (do_gelu) v = gelu_f(v);
                size_t idx = (size_t)rg * N + cg;
                if (res1f) v += res1f[idx];
                if (resi1) v += bf2f(resi1[idx]);
                if (resi2) v += bf2f(resi2[idx]);
                size_t dst;
                if (mode == 1) {   // fused QKV: cg in [0,3072)
                    int which = cg >> 10, wr2 = cg & 1023;
                    int h = wr2 >> 6, dk = wr2 & 63;
                    int b = rg >> 10, s = rg & 1023;
                    dst = (size_t)which * ((size_t)ROWS * Dc)
                        + (((size_t)b * Hc + h) * Sc_ + s) * DKc + dk;
                } else dst = idx;
                if constexpr (sizeof(OutT) == 4) outg[dst] = v;
                else                             outg[dst] = f2bf(v);
            }
        }
    }
}

// ---- gemm8_bt: 8-phase 256x256, BK=64, 512 threads (FF1, QKV) ----
// Halves: A-half qm = 64-row stripes ((row>>6)&1), B-half qn = 32-row stripes
// ((row>>5)&1) -> phase (qm,qn) needs exactly halves (A_qm, B_qn). Stage order
// per tile: A0,B0,B1,A1 at phases 0..3 into buf^1; issue BEFORE vmcnt(6) so 3
// half-tiles stay in flight across barriers. Tail tile drains vmcnt 4->2->0->0.
// LDS chunk-XOR swizzle (pre-swizzled glds source + swizzled ds_read): 2-way free.
template<typename OutT>
__global__ __launch_bounds__(512, 2) void gemm8_bt(
    const ushort* __restrict__ Ag, const ushort* __restrict__ Wt,
    const float* __restrict__ biasg, OutT* __restrict__ outg,
    int N, int K, int do_gelu, int mode) {
    __shared__ ushort Al[2][16384];   // [buf][half*8192 + rl*64 + pch*8]
    __shared__ ushort Bl[2][16384];
    const int tid = threadIdx.x;
    const int wave = tid >> 6, lane = tid & 63;
    const int quad = lane >> 4, l16 = lane & 15;
    const int wm = (wave >> 2) * 128, wn = (wave & 3) * 64;
    const int m0 = blockIdx.y * 256, n0 = blockIdx.x * 256;

    float4v acc[8][4];
    const float4v zero = {0.f, 0.f, 0.f, 0.f};
#pragma unroll
    for (int i = 0; i < 8; i++)
#pragma unroll
        for (int j = 0; j < 4; j++) acc[i][j] = zero;

    // stage one half-tile (128 rows x 64 K = 16KB), 2 glds/thread.
    // which: 0=A half0, 1=B half0, 2=B half1, 3=A half1
    auto stageH = [&](int buf, int k0, int which) {
#pragma unroll
        for (int it = 0; it < 2; it++) {
            int s = tid + it * 512;            // slot 0..1023
            int rl = s >> 3, pch = s & 7;
            int ch = pch ^ (rl & 7);           // pre-swizzled source chunk
            const ushort* src; ushort* dst;
            if (which == 0)      { int row = ((rl >> 6) << 7) + (rl & 63);
                                   src = Ag + (size_t)(m0 + row) * K + k0 + ch * 8;
                                   dst = &Al[buf][s * 8]; }
            else if (which == 1) { int row = ((rl >> 5) << 6) + (rl & 31);
                                   src = Wt + (size_t)(n0 + row) * K + k0 + ch * 8;
                                   dst = &Bl[buf][s * 8]; }
            else if (which == 2) { int row = ((rl >> 5) << 6) + 32 + (rl & 31);
                                   src = Wt + (size_t)(n0 + row) * K + k0 + ch * 8;
                                   dst = &Bl[buf][8192 + s * 8]; }
            else                 { int row = ((rl >> 6) << 7) + 64 + (rl & 63);
                                   src = Ag + (size_t)(m0 + row) * K + k0 + ch * 8;
                                   dst = &Al[buf][8192 + s * 8]; }
            async_copy16(dst, src);
        }
    };

    const int rlA = ((wm >> 7) << 6) + l16;   // row-within-half base for A reads
    const int rlB = ((wn >> 6) << 5) + l16;   // for B reads
    const int sw  = l16 & 7;                  // read-side swizzle (== rl&7)

    const int nt = K >> 6;                    // K/64 tiles
    // prologue: all 4 halves of tile 0 (8 loads in flight)
    stageH(0, 0, 0); stageH(0, 0, 1); stageH(0, 0, 2); stageH(0, 0, 3);

#define G8_SYNC(WHICH, VMLAST)                                            \
    __builtin_amdgcn_sched_barrier(0);                                    \
    if (more) { stageH(nbuf, knext, WHICH);                               \
                __builtin_amdgcn_sched_barrier(0);                        \
                __builtin_amdgcn_s_waitcnt(0x0F76); /* vmcnt(6) */        \
    } else   { __builtin_amdgcn_s_waitcnt(VMLAST); }                      \
    __builtin_amdgcn_s_barrier();                                         \
    __builtin_amdgcn_sched_barrier(0);

#define G8_COMPUTE(QM, QN, LOADA)                                         \
    if (LOADA) {                                                          \
        _Pragma("unroll") for (int kk = 0; kk < 2; kk++)                  \
        _Pragma("unroll") for (int i = 0; i < 4; i++)                     \
            af[kk][i] = *reinterpret_cast<const short8*>(                 \
                &Al[buf][(QM) * 8192 + (rlA + i * 16) * 64 +              \
                         (((kk << 2) | quad) ^ sw) * 8]);                 \
    }                                                                     \
    _Pragma("unroll") for (int kk = 0; kk < 2; kk++)                      \
    _Pragma("unroll") for (int j = 0; j < 2; j++)                         \
        bfr[kk][j] = *reinterpret_cast<const short8*>(                    \
            &Bl[buf][(QN) * 8192 + (rlB + j * 16) * 64 +                  \
                     (((kk << 2) | quad) ^ sw) * 8]);                     \
    __builtin_amdgcn_s_setprio(1);                                        \
    _Pragma("unroll") for (int kk = 0; kk < 2; kk++)                      \
    _Pragma("unroll") for (int i = 0; i < 4; i++)                         \
    _Pragma("unroll") for (int j = 0; j < 2; j++)                         \
        acc[(QM) * 4 + i][(QN) * 2 + j] =                                 \
            __builtin_amdgcn_mfma_f32_16x16x32_bf16(                      \
                as_bf(af[kk][i]), as_bf(bfr[kk][j]),                      \
                acc[(QM) * 4 + i][(QN) * 2 + j], 0, 0, 0);                \
    __builtin_amdgcn_s_setprio(0);

    for (int t = 0; t < nt; ++t) {
        const int buf = t & 1, nbuf = buf ^ 1;
        const int knext = (t + 1) << 6;
        const bool more = (t + 1 < nt);
        short8 af[2][4], bfr[2][2];
        G8_SYNC(0, 0x0F74)  G8_COMPUTE(0, 0, true)    // needs A0,B0
        G8_SYNC(1, 0x0F72)  G8_COMPUTE(0, 1, false)   // needs B1 (A0 cached)
        G8_SYNC(2, 0x0F70)  G8_COMPUTE(1, 0, true)    // needs A1
        G8_SYNC(3, 0x0F70)  G8_COMPUTE(1, 1, false)   // all
    }
#undef G8_SYNC
#undef G8_COMPUTE

    // epilogue: C/D col=l16 (n), row=quad*4+r (m)
#pragma unroll
    for (int jg = 0; jg < 4; jg++) {
        int cg = n0 + wn + jg * 16 + l16;
        float bv = biasg ? biasg[cg] : 0.f;
#pragma unroll
        for (int ig = 0; ig < 8; ig++) {
#pragma unroll
            for (int r = 0; r < 4; r++) {
                int rg = m0 + wm + ig * 16 + quad * 4 + r;
                float v = acc[ig][jg][r] + bv;
                if (do_gelu) v = gelu_f(v);
                size_t dst;
                if (mode == 1) {   // fused QKV scatter
                    int which = cg >> 10, wr2 = cg & 1023;
                    int h = wr2 >> 6, dk = wr2 & 63;
                    int b = rg >> 10, s = rg & 1023;
                    dst = (size_t)which * ((size_t)ROWS * Dc)
                        + (((size_t)b * Hc + h) * Sc_ + s) * DKc + dk;
                } else dst = (size_t)rg * N + cg;
                if constexpr (sizeof(OutT) == 4) outg[dst] = v;
                else                             outg[dst] = f2bf(v);
            }
        }
    }
}

// ---- Attention: register flash, defer-max, LDS-staged K/V (glds double-buffer) ----
__global__ __launch_bounds__(256, 4) void attn_kernel(
    const ushort* __restrict__ Qg, const ushort* __restrict__ Kg,
    const ushort* __restrict__ Vt, const float* __restrict__ relg,
    ushort* __restrict__ ctxg) {
    __shared__ ushort Kl[2][2048];   // 32 rows x 64 elem (128B), chunk-swizzled
    __shared__ ushort Vl[2][2048];   // 64 rows x 32 elem (64B),  chunk-swizzled
    __shared__ float Tpad[1088];     // bias[j] = tab[clamp(j - qb, 0, 126)]
    constexpr float L2E = 1.44269504f;

    const int blk = blockIdx.x;
    const int vb = (blk & 7) * 128 + (blk >> 3);
    const int bh = vb >> 4;            // [0,64)
    const int qblk = vb & 15;          // [0,16)
    const int h = bh & (Hc - 1);
    const int b = bh >> 4;
    const int qb = qblk * 64;
    const int tid = threadIdx.x;
    const int wave = tid >> 6, lane = tid & 63;
    const int quad = lane >> 4, l16 = lane & 15;
    const int ql = wave * 16 + l16;    // block-relative q row of this lane

    const ushort* Kbh  = Kg + (size_t)bh * Sc_ * DKc;
    const ushort* Vtbh = Vt + (size_t)bh * DKc * Sc_;

    auto stage = [&](int buf, int t0) {
        {   // K: slot (r, ch) <- global chunk (r, ch ^ (r&7))
            int r = tid >> 3, ch = tid & 7;
            const ushort* src = Kbh + (size_t)(t0 + r) * DKc + ((ch ^ (r & 7)) * 8);
            async_copy16(&Kl[buf][tid * 8], src);
        }
        {   // V: slot (d, ch) <- global chunk (d, ch ^ ((d>>1)&3))
            int d = tid >> 2, ch = tid & 3;
            const ushort* src = Vtbh + (size_t)d * Sc_ + t0 + ((ch ^ ((d >> 1) & 3)) * 8);
            async_copy16(&Vl[buf][tid * 8], src);
        }
    };

    stage(0, 0);   // prologue (drained by the __syncthreads below)

    for (int j = tid; j < 1087; j += 256) {
        int r = min(max(j - qb, 0), 126);
        Tpad[j] = relg[r * Hc + h];
    }

    short8 aQ[2];
    {
        const ushort* qrow = Qg + ((size_t)bh * Sc_ + qb + ql) * DKc + quad * 8;
#pragma unroll
        for (int f = 0; f < 2; f++) {
            short8 v = *reinterpret_cast<const short8*>(qrow + f * 32);
#pragma unroll
            for (int e = 0; e < 8; e++) v[e] = (short)f2bf(bf2f((ushort)v[e]) * 0.125f);
            aQ[f] = v;
        }
    }
    __syncthreads();   // Tpad + prologue stage complete

    float4v accO[4];
#pragma unroll
    for (int i = 0; i < 4; i++) accO[i] = float4v{0.f, 0.f, 0.f, 0.f};
    float m = -1e30f, lsum = 0.f;
    float ml2 = m * L2E;
    const int srcA = ((quad & 1) * 2) * 16 + l16;
    const int srcB = srcA + 16;
    const bool hi = quad >= 2;

    auto compute = [&](int buf, int t0) {
        short8 vf[4];
#pragma unroll
        for (int dt = 0; dt < 4; dt++) {
            int d = dt * 16 + l16;
            vf[dt] = *reinterpret_cast<const short8*>(
                &Vl[buf][d * 32 + ((quad ^ ((l16 >> 1) & 3)) * 8)]);
        }
        short8 kf[2][2];
#pragma unroll
        for (int kt = 0; kt < 2; kt++)
#pragma unroll
            for (int f = 0; f < 2; f++)
                kf[kt][f] = *reinterpret_cast<const short8*>(
                    &Kl[buf][(kt * 16 + l16) * 64 + (((f * 4 + quad) ^ (l16 & 7)) * 8)]);

        const int jb = t0 + quad * 4 - ql + 63;
        float4v c0 = { Tpad[jb],      Tpad[jb + 1],  Tpad[jb + 2],  Tpad[jb + 3]  };
        float4v c1 = { Tpad[jb + 16], Tpad[jb + 17], Tpad[jb + 18], Tpad[jb + 19] };

        float4v s0 = __builtin_amdgcn_mfma_f32_16x16x32_bf16(as_bf(kf[0][0]), as_bf(aQ[0]), c0, 0, 0, 0);
        s0 = __builtin_amdgcn_mfma_f32_16x16x32_bf16(as_bf(kf[0][1]), as_bf(aQ[1]), s0, 0, 0, 0);
        float4v s1 = __builtin_amdgcn_mfma_f32_16x16x32_bf16(as_bf(kf[1][0]), as_bf(aQ[0]), c1, 0, 0, 0);
        s1 = __builtin_amdgcn_mfma_f32_16x16x32_bf16(as_bf(kf[1][1]), as_bf(aQ[1]), s1, 0, 0, 0);

        float lt = fmaxf(fmaxf(fmaxf(s0[0], s0[1]), fmaxf(s0[2], s0[3])),
                         fmaxf(fmaxf(s1[0], s1[1]), fmaxf(s1[2], s1[3])));
        if (!__all(lt <= m + 8.f)) {
            float tmax = fmaxf(lt, __shfl_xor(lt, 16));
            tmax = fmaxf(tmax, __shfl_xor(tmax, 32));
            float mn = fmaxf(m, tmax);
            float sc = exp2_hw((m - mn) * L2E);
            m = mn; ml2 = m * L2E;
            lsum *= sc;
#pragma unroll
            for (int dt = 0; dt < 4; dt++)
#pragma unroll
                for (int r = 0; r < 4; r++) accO[dt][r] *= sc;
        }
        float p0[4], p1[4];
#pragma unroll
        for (int r = 0; r < 4; r++) {
            p0[r] = exp2_hw(fmaf(s0[r], L2E, -ml2));
            p1[r] = exp2_hw(fmaf(s1[r], L2E, -ml2));
        }
        lsum += ((p0[0] + p0[1]) + (p0[2] + p0[3]))
              + ((p1[0] + p1[1]) + (p1[2] + p1[3]));

        uint w0 = cvt_pk_bf16(p0[0], p0[1]);
        uint w1 = cvt_pk_bf16(p0[2], p0[3]);
        uint w2 = cvt_pk_bf16(p1[0], p1[1]);
        uint w3 = cvt_pk_bf16(p1[2], p1[3]);
        uint a0 = __shfl(w0, srcA), a1 = __shfl(w1, srcA);
        uint a2 = __shfl(w2, srcA), a3 = __shfl(w3, srcA);
        uint b0 = __shfl(w0, srcB), b1 = __shfl(w1, srcB);
        uint b2 = __shfl(w2, srcB), b3 = __shfl(w3, srcB);
        union { uint u[4]; short8 s; } pf;
        pf.u[0] = hi ? a2 : a0;
        pf.u[1] = hi ? a3 : a1;
        pf.u[2] = hi ? b2 : b0;
        pf.u[3] = hi ? b3 : b1;

#pragma unroll
        for (int dt = 0; dt < 4; dt++)
            accO[dt] = __builtin_amdgcn_mfma_f32_16x16x32_bf16(as_bf(vf[dt]), as_bf(pf.s), accO[dt], 0, 0, 0);
    };

    for (int t0 = 0; t0 < Sc_; t0 += 64) {
        __builtin_amdgcn_sched_barrier(0);
        __builtin_amdgcn_s_waitcnt(0x0F70);   // vmcnt(0): stage(buf0) done
        __builtin_amdgcn_s_barrier();
        __builtin_amdgcn_sched_barrier(0);
        stage(1, t0 + 32);
        __builtin_amdgcn_sched_barrier(0);
        compute(0, t0);

        __builtin_amdgcn_sched_barrier(0);
        __builtin_amdgcn_s_waitcnt(0x0F70);   // vmcnt(0): stage(buf1) done
        __builtin_amdgcn_s_barrier();
        __builtin_amdgcn_sched_barrier(0);
        if (t0 + 64 < Sc_) stage(0, t0 + 64);
        __builtin_amdgcn_sched_barrier(0);
        compute(1, t0 + 32);
    }

    lsum += __shfl_xor(lsum, 16);
    lsum += __shfl_xor(lsum, 32);
    float linv = 1.f / lsum;

    const int s = qb + ql;
    ushort* orow = ctxg + ((size_t)b * Sc_ + s) * Dc + h * DKc + quad * 4;
#pragma unroll
    for (int dt = 0; dt < 4; dt++) {
        uint2v o;
        o[0] = cvt_pk_bf16(accO[dt][0] * linv, accO[dt][1] * linv);
        o[1] = cvt_pk_bf16(accO[dt][2] * linv, accO[dt][3] * linv);
        *reinterpret_cast<uint2v*>(orow + dt * 16) = o;
    }
}

extern "C" void kernel_launch(void* const* d_in, const int* in_sizes, int n_in,
                              void* d_out, int out_size, void* d_ws, size_t ws_size,
                              hipStream_t stream) {
    float* out = (float*)d_out;

    static const int exp_sizes[22] = {
        4194304, 1048576, 1024, 1048576, 1024, 1048576, 1024, 1048576, 1024,
        2032, 1024, 1024, 1024, 1024, 4194304, 4096, 4194304, 1024,
        1048576, 1024, 1024, 1024};
    bool ok = (n_in == 22);
    if (ok) for (int i = 0; i < 22; i++) if (in_sizes[i] != exp_sizes[i]) { ok = false; break; }
    if (!ok) {
        sentinel_kernel<<<(out_size + 255) / 256, 256, 0, stream>>>(out, out_size);
        return;
    }

    const float* x   = (const float*)d_in[0];
    const float* wq  = (const float*)d_in[1];  const float* bq  = (const float*)d_in[2];
    const float* wk  = (const float*)d_in[3];  const float* bk  = (const float*)d_in[4];
    const float* wv  = (const float*)d_in[5];  const float* bv  = (const float*)d_in[6];
    const float* wo  = (const float*)d_in[7];  const float* bo  = (const float*)d_in[8];
    const float* rel = (const float*)d_in[9];
    const float* g1  = (const float*)d_in[10]; const float* be1 = (const float*)d_in[11];
    const float* g2  = (const float*)d_in[12]; const float* be2 = (const float*)d_in[13];
    const float* w1  = (const float*)d_in[14]; const float* b1  = (const float*)d_in[15];
    const float* w2  = (const float*)d_in[16]; const float* b2  = (const float*)d_in[17];
    const float* w3  = (const float*)d_in[18]; const float* b3  = (const float*)d_in[19];
    const float* gf  = (const float*)d_in[20]; const float* bfp = (const float*)d_in[21];

    // ws (64 MiB = 8*NE shorts): [0]=Wts [1]=nx/ctx/yb [2]=Qb/x1 [3]=Kb/nx2/ly
    // [4]=Vb [5]=Vt [4..7]=hb (FF phase); bqkv floats at [6] (QKV phase only)
    constexpr size_t NE = (size_t)ROWS * Dc;   // 4M elements
    ushort* base = (ushort*)d_ws;
    ushort* Wts  = base;
    ushort* nx   = base + NE;
    ushort* Qb   = base + 2 * NE;              // Kb=Qb+NE, Vb=Qb+2NE contiguous
    ushort* Kb   = base + 3 * NE;
    ushort* Vb   = base + 4 * NE;
    ushort* Vt   = base + 5 * NE;
    float*  bqkv = (float*)(base + 6 * NE);
    ushort* ctx  = nx;
    ushort* x1   = Qb;
    ushort* nx2  = Kb;
    ushort* hb   = base + 4 * NE;              // 4NE shorts = 32MB
    ushort* yb   = nx;
    ushort* ly   = Kb;

    dim3 blk(256);
    dim3 blk8(512);
    dim3 gQKV(3072 / 256, ROWS / 256);  // (12, 16) 256x256 8-phase
    dim3 gD(ROWS / 64, Dc / 128);       // (64, 8)  m-fast 2-phase
    dim3 gFF(DFFc / 256, ROWS / 256);   // (16, 16) 256x256 8-phase
    dim3 cD(Dc / 64, Dc / 64);
    dim3 c1(DFFc / 64, Dc / 64);
    dim3 c2(Dc / 64, DFFc / 64);
    dim3 cV(Sc_ / 64, Bc * Hc);

    ln_kernel<true><<<ROWS, blk, 0, stream>>>(x, g1, be1, nx);
    wconv_kernel<<<cD, blk, 0, stream>>>(wq, Wts, Dc, Dc);
    wconv_kernel<<<cD, blk, 0, stream>>>(wk, Wts + (size_t)1024 * 1024, Dc, Dc);
    wconv_kernel<<<cD, blk, 0, stream>>>(wv, Wts + (size_t)2048 * 1024, Dc, Dc);
    bias3_kernel<<<12, blk, 0, stream>>>(bq, bk, bv, bqkv);
    gemm8_bt<ushort><<<gQKV, blk8, 0, stream>>>(nx, Wts, bqkv, Qb, 3072, Dc, 0, 1);
    vconv_kernel<<<cV, blk, 0, stream>>>(Vb, Vt);
    attn_kernel<<<dim3(1024), blk, 0, stream>>>(Qb, Kb, Vt, rel, ctx);
    wconv_kernel<<<cD, blk, 0, stream>>>(wo, Wts, Dc, Dc);
    gemm_bt<64, 128, ushort><<<gD, blk, 0, stream>>>(ctx, Wts, bo, x, nullptr, nullptr, x1, ROWS, Dc, Dc, 0, 0);
    ln_kernel<false><<<ROWS, blk, 0, stream>>>(x1, g2, be2, nx2);
    wconv_kernel<<<c1, blk, 0, stream>>>(w1, Wts, Dc, DFFc);
    gemm8_bt<ushort><<<gFF, blk8, 0, stream>>>(nx2, Wts, b1, hb, DFFc, Dc, 1, 0);
    wconv_kernel<<<c2, blk, 0, stream>>>(w2, Wts, DFFc, Dc);
    gemm_bt<64, 128, ushort><<<gD, blk, 0, stream>>>(hb, Wts, b2, nullptr, nx2, nullptr, yb, ROWS, Dc, DFFc, 0, 0);
    ln_kernel<false><<<ROWS, blk, 0, stream>>>(yb, gf, bfp, ly);
    wconv_kernel<<<cD, blk, 0, stream>>>(w3, Wts, Dc, Dc);
    gemm_bt<64, 128, float><<<gD, blk, 0, stream>>>(ly, Wts, b3, nullptr, x1, yb, out, ROWS, Dc, Dc, 0, 0);
}

// Round 7
// 441.973 us; speedup vs baseline: 1.0213x; 1.0213x over previous
//
#include <hip/hip_runtime.h>
#include <hip/hip_bf16.h>
#include <math.h>

// TransformerBlock B=4,S=1024,D=1024,H=16,DK=64,DFF=4096. Externals f32, out f32.
// GEMMs: wconv (f32 W -> Wt[N][K] bf16). Two GEMM engines:
//  - gemm_bt: 3-buffer counted-vmcnt pipeline, 64x128 tiles (QKV/proj/FF2/out,
//    m-fast grid -> XCD=m%8). Per iter: vmcnt(L) waits only for loads issued TWO
//    compute phases ago; stage i+2 AFTER the barrier (race-free: buffer (i-1)%3
//    is finished by all waves at the rendezvous). No vmcnt(0) in main loop.
//    K-accumulation order identical to the validated 2-phase engine.
//  - gemm8_bt: 8-phase 256x256 (FF1 only; 256 blocks = 1/CU design point).
// Attention: register flash, defer-max, LDS-staged K/V glds double-buffer.

constexpr int Bc = 4, Sc_ = 1024, Dc = 1024, Hc = 16, DKc = 64, DFFc = 4096;
constexpr int ROWS = Bc * Sc_;   // 4096
constexpr int BK = 32;

typedef short short8 __attribute__((ext_vector_type(8)));
typedef __bf16 bf16x8 __attribute__((ext_vector_type(8)));
typedef float float4v __attribute__((ext_vector_type(4)));
typedef uint uint2v __attribute__((ext_vector_type(2)));

__device__ __forceinline__ float bf2f(ushort u) {
    union { uint i; float f; } v; v.i = ((uint)u) << 16; return v.f;
}
__device__ __forceinline__ ushort f2bf(float f) {
    union { float f; uint i; } v; v.f = f;
    uint r = v.i + 0x7FFF + ((v.i >> 16) & 1);   // RNE
    return (ushort)(r >> 16);
}
__device__ __forceinline__ bf16x8 as_bf(short8 s) {
    union { short8 s; bf16x8 b; } u; u.s = s; return u.b;
}
__device__ __forceinline__ uint cvt_pk_bf16(float lo, float hi) {
    uint r;
    asm("v_cvt_pk_bf16_f32 %0, %1, %2" : "=v"(r) : "v"(lo), "v"(hi));
    return r;
}
__device__ __forceinline__ float exp2_hw(float x) {   // v_exp_f32: 2^x, ~1 ulp
    float r;
    asm("v_exp_f32 %0, %1" : "=v"(r) : "v"(x));
    return r;
}
__device__ __forceinline__ void async_copy16(void* lds, const void* g) {
    __builtin_amdgcn_global_load_lds((const __attribute__((address_space(1))) uint*)g,
                                     (__attribute__((address_space(3))) uint*)lds, 16, 0, 0);
}
// exact-GELU via Abramowitz-Stegun erf (max abs err 1.5e-7)
__device__ __forceinline__ float gelu_f(float v) {
    float z = v * 0.70710678118654752f;
    float az = fabsf(z);
    float t = 1.f / (1.f + 0.3275911f * az);
    float p = ((((1.061405429f * t - 1.453152027f) * t) + 1.421413741f) * t
               - 0.284496736f) * t + 0.254829592f;
    float y = 1.f - p * t * __expf(-az * az);
    float er = (z < 0.f) ? -y : y;
    return 0.5f * v * (1.f + er);
}

__global__ void sentinel_kernel(float* __restrict__ out, int n) {
    int i = blockIdx.x * 256 + threadIdx.x;
    if (i < n) out[i] = 100.0f;
}

// combined qkv bias
__global__ void bias3_kernel(const float* __restrict__ a, const float* __restrict__ b,
                             const float* __restrict__ c, float* __restrict__ o) {
    int i = blockIdx.x * 256 + threadIdx.x;
    if (i < 1024) o[i] = a[i];
    else if (i < 2048) o[i] = b[i - 1024];
    else if (i < 3072) o[i] = c[i - 2048];
}

// ---- transpose+convert: W[K][N] f32 -> Wt[N][K] bf16, 64x64 tiles ----
__global__ __launch_bounds__(256) void wconv_kernel(const float* __restrict__ W,
                                                    ushort* __restrict__ Wt,
                                                    int K, int N) {
    __shared__ float T[64][65];
    const int kt = blockIdx.y * 64, nt = blockIdx.x * 64;
    const int tid = threadIdx.x;
#pragma unroll
    for (int it = 0; it < 4; it++) {
        int r = it * 16 + (tid >> 4), c = (tid & 15) * 4;
        float4v v = *reinterpret_cast<const float4v*>(W + (size_t)(kt + r) * N + nt + c);
        T[r][c] = v[0]; T[r][c + 1] = v[1]; T[r][c + 2] = v[2]; T[r][c + 3] = v[3];
    }
    __syncthreads();
    int n = tid >> 2, kc = (tid & 3) * 16;
    short8 a, b;
#pragma unroll
    for (int q = 0; q < 8; q++) {
        a[q] = (short)f2bf(T[kc + q][n]);
        b[q] = (short)f2bf(T[kc + 8 + q][n]);
    }
    ushort* dst = Wt + (size_t)(nt + n) * K + kt + kc;
    *reinterpret_cast<short8*>(dst) = a;
    *reinterpret_cast<short8*>(dst + 8) = b;
}

// ---- V transpose: V[b,h,s,dk] bf16 -> Vt[b,h,dk,s] bf16 ----
__global__ __launch_bounds__(256) void vconv_kernel(const ushort* __restrict__ V,
                                                    ushort* __restrict__ Vt) {
    __shared__ ushort T[64][65];
    const int bh = blockIdx.y;
    const int s0 = blockIdx.x * 64;
    const int tid = threadIdx.x;
    const int r = tid >> 2, c = (tid & 3) * 16;
    const ushort* src = V + ((size_t)bh * Sc_ + s0 + r) * DKc + c;
    short8 a = *reinterpret_cast<const short8*>(src);
    short8 b = *reinterpret_cast<const short8*>(src + 8);
#pragma unroll
    for (int q = 0; q < 8; q++) { T[r][c + q] = (ushort)a[q]; T[r][c + 8 + q] = (ushort)b[q]; }
    __syncthreads();
    const int dk = tid >> 2, sc2 = (tid & 3) * 16;
    short8 o0, o1;
#pragma unroll
    for (int q = 0; q < 8; q++) { o0[q] = (short)T[sc2 + q][dk]; o1[q] = (short)T[sc2 + 8 + q][dk]; }
    ushort* dst = Vt + ((size_t)bh * DKc + dk) * Sc_ + s0 + sc2;
    *reinterpret_cast<short8*>(dst) = o0;
    *reinterpret_cast<short8*>(dst + 8) = o1;
}

// ---- LayerNorm: one block per row of D=1024 ----
template<bool IN_F32>
__global__ __launch_bounds__(256) void ln_kernel(const void* __restrict__ xin,
                                                 const float* __restrict__ g,
                                                 const float* __restrict__ be,
                                                 ushort* __restrict__ out) {
    int row = blockIdx.x;
    int tid = threadIdx.x;
    float v0[4], s = 0.f, ss = 0.f;
#pragma unroll
    for (int i = 0; i < 4; i++) {
        int c = tid + i * 256;
        float f = IN_F32 ? ((const float*)xin)[(size_t)row * Dc + c]
                         : bf2f(((const ushort*)xin)[(size_t)row * Dc + c]);
        v0[i] = f; s += f; ss += f * f;
    }
#pragma unroll
    for (int off = 32; off > 0; off >>= 1) {
        s += __shfl_down(s, off);
        ss += __shfl_down(ss, off);
    }
    __shared__ float red[8];
    __shared__ float stat[2];
    int wave = tid >> 6, lane = tid & 63;
    if (lane == 0) { red[wave] = s; red[wave + 4] = ss; }
    __syncthreads();
    if (tid == 0) {
        float a = 0.f, b = 0.f;
        for (int w = 0; w < 4; w++) { a += red[w]; b += red[w + 4]; }
        stat[0] = a; stat[1] = b;
    }
    __syncthreads();
    float mean = stat[0] * (1.f / Dc);
    float var  = stat[1] * (1.f / Dc) - mean * mean;
    float inv  = rsqrtf(var + 1e-5f);
#pragma unroll
    for (int i = 0; i < 4; i++) {
        int c = tid + i * 256;
        float nv = (v0[i] - mean) * inv * g[c] + be[c];
        out[(size_t)row * Dc + c] = f2bf(nv);
    }
}

// ---- bt-GEMM, 3-buffer counted-vmcnt pipeline (QKV / proj / FF2 / out) ----
// vmcnt(L) waits for tile-i loads issued two compute phases ago; stage(i+2)
// AFTER the barrier (overwrites buf (i-1)%3, finished by all waves). K-order
// identical to the 2-phase engine -> bit-identical outputs.
template<int BM, int BN, typename OutT>
__global__ __launch_bounds__(256) void gemm_bt(
    const ushort* __restrict__ Ag, const ushort* __restrict__ Wt,
    const float* __restrict__ biasg,
    const float* __restrict__ res1f,
    const ushort* __restrict__ resi1, const ushort* __restrict__ resi2,
    OutT* __restrict__ outg,
    int M, int N, int K, int do_gelu, int mode) {
    constexpr int WN = BN / 64;            // waves along n
    constexpr int WM = 4 / WN;             // waves along m
    constexpr int MI = BM / (WM * 16);     // m-frags per wave
    constexpr int TSZ = (BM + BN) * BK;    // shorts per LDS buffer
    constexpr int TOT = (BM + BN) * 4;     // 16B chunks per buffer
    constexpr int LPT = TOT / 256;         // glds per thread per tile
    constexpr unsigned VM_L = 0x0F70 | (unsigned)LPT;   // vmcnt(LPT), LPT<16
    __shared__ ushort Tile[3 * TSZ];
    const int tid = threadIdx.x;
    const int wave = tid >> 6, lane = tid & 63;
    const int quad = lane >> 4, l16 = lane & 15;
    const int m0 = blockIdx.x * BM, n0 = blockIdx.y * BN;
    const int wm = (wave / WN) * (MI * 16), wn = (wave % WN) * 64;

    float4v acc[MI][4];
    const float4v zero = {0.f, 0.f, 0.f, 0.f};
#pragma unroll
    for (int i = 0; i < MI; i++)
#pragma unroll
        for (int j = 0; j < 4; j++) acc[i][j] = zero;

    auto stage = [&](int buf, int k0) {
#pragma unroll
        for (int it = 0; it < LPT; it++) {
            int c = tid + it * 256;
            int row = c >> 2, kc = (c & 3) * 8;
            const ushort* src = (row < BM)
                ? Ag + (size_t)(m0 + row) * K + k0 + kc
                : Wt + (size_t)(n0 + row - BM) * K + k0 + kc;
            async_copy16(&Tile[buf * TSZ + c * 8], src);
        }
    };

    const int nit = K / BK;
    stage(0, 0);
    stage(1, BK);
    int bc = 0, bs = 2;                    // compute buf, stage buf = (i+2)%3
    for (int i = 0; i < nit; i++) {
        __builtin_amdgcn_sched_barrier(0);
        if (i + 1 < nit) __builtin_amdgcn_s_waitcnt(VM_L);      // tile i done
        else             __builtin_amdgcn_s_waitcnt(0x0F70);    // last: drain
        __builtin_amdgcn_s_barrier();
        __builtin_amdgcn_sched_barrier(0);
        if (i + 2 < nit) stage(bs, (i + 2) * BK);   // overlaps compute below
        const ushort* Asb = &Tile[bc * TSZ];
        const ushort* Bsb = &Tile[bc * TSZ + BM * BK];
        short8 af[MI], bfr[4];
#pragma unroll
        for (int ii = 0; ii < MI; ii++)
            af[ii] = *reinterpret_cast<const short8*>(&Asb[(wm + ii * 16 + l16) * BK + quad * 8]);
#pragma unroll
        for (int j = 0; j < 4; j++)
            bfr[j] = *reinterpret_cast<const short8*>(&Bsb[(wn + j * 16 + l16) * BK + quad * 8]);
#pragma unroll
        for (int j = 0; j < 4; j++)
#pragma unroll
            for (int ii = 0; ii < MI; ii++)
                acc[ii][j] = __builtin_amdgcn_mfma_f32_16x16x32_bf16(as_bf(af[ii]), as_bf(bfr[j]), acc[ii][j], 0, 0, 0);
        bc = (bc == 2) ? 0 : bc + 1;
        bs = (bs == 2) ? 0 : bs + 1;
    }
    __builtin_amdgcn_s_barrier();

    // epilogue: C/D layout col=lane&15, row=quad*4+reg
#pragma unroll
    for (int j = 0; j < 4; j++) {
        int cg = n0 + wn + j * 16 + l16;
        float bv = biasg ? biasg[cg] : 0.f;
#pragma unroll
        for (int i = 0; i < MI; i++) {
#pragma unroll
            for (int r = 0; r < 4; r++) {
                int rg = m0 + wm + i * 16 + quad * 4 + r;
                float v = acc[i][j][r] + bv;
                if (do_gelu) v = gelu_f(v);
                size_t idx = (size_t)rg * N + cg;
                if (res1f) v += res1f[idx];
                if (resi1) v += bf2f(resi1[idx]);
                if (resi2) v += bf2f(resi2[idx]);
                size_t dst;
                if (mode == 1) {   // fused QKV: cg in [0,3072)
                    int which = cg >> 10, wr2 = cg & 1023;
                    int h = wr2 >> 6, dk = wr2 & 63;
                    int b = rg >> 10, s = rg & 1023;
                    dst = (size_t)which * ((size_t)ROWS * Dc)
                        + (((size_t)b * Hc + h) * Sc_ + s) * DKc + dk;
                } else dst = idx;
                if constexpr (sizeof(OutT) == 4) outg[dst] = v;
                else                             outg[dst] = f2bf(v);
            }
        }
    }
}

// ---- gemm8_bt: 8-phase 256x256, BK=64, 512 threads (FF1) ----
template<typename OutT>
__global__ __launch_bounds__(512, 2) void gemm8_bt(
    const ushort* __restrict__ Ag, const ushort* __restrict__ Wt,
    const float* __restrict__ biasg, OutT* __restrict__ outg,
    int N, int K, int do_gelu, int mode) {
    __shared__ ushort Al[2][16384];   // [buf][half*8192 + rl*64 + pch*8]
    __shared__ ushort Bl[2][16384];
    const int tid = threadIdx.x;
    const int wave = tid >> 6, lane = tid & 63;
    const int quad = lane >> 4, l16 = lane & 15;
    const int wm = (wave >> 2) * 128, wn = (wave & 3) * 64;
    const int m0 = blockIdx.y * 256, n0 = blockIdx.x * 256;

    float4v acc[8][4];
    const float4v zero = {0.f, 0.f, 0.f, 0.f};
#pragma unroll
    for (int i = 0; i < 8; i++)
#pragma unroll
        for (int j = 0; j < 4; j++) acc[i][j] = zero;

    auto stageH = [&](int buf, int k0, int which) {
#pragma unroll
        for (int it = 0; it < 2; it++) {
            int s = tid + it * 512;            // slot 0..1023
            int rl = s >> 3, pch = s & 7;
            int ch = pch ^ (rl & 7);           // pre-swizzled source chunk
            const ushort* src; ushort* dst;
            if (which == 0)      { int row = ((rl >> 6) << 7) + (rl & 63);
                                   src = Ag + (size_t)(m0 + row) * K + k0 + ch * 8;
                                   dst = &Al[buf][s * 8]; }
            else if (which == 1) { int row = ((rl >> 5) << 6) + (rl & 31);
                                   src = Wt + (size_t)(n0 + row) * K + k0 + ch * 8;
                                   dst = &Bl[buf][s * 8]; }
            else if (which == 2) { int row = ((rl >> 5) << 6) + 32 + (rl & 31);
                                   src = Wt + (size_t)(n0 + row) * K + k0 + ch * 8;
                                   dst = &Bl[buf][8192 + s * 8]; }
            else                 { int row = ((rl >> 6) << 7) + 64 + (rl & 63);
                                   src = Ag + (size_t)(m0 + row) * K + k0 + ch * 8;
                                   dst = &Al[buf][8192 + s * 8]; }
            async_copy16(dst, src);
        }
    };

    const int rlA = ((wm >> 7) << 6) + l16;   // row-within-half base for A reads
    const int rlB = ((wn >> 6) << 5) + l16;   // for B reads
    const int sw  = l16 & 7;                  // read-side swizzle (== rl&7)

    const int nt = K >> 6;                    // K/64 tiles
    stageH(0, 0, 0); stageH(0, 0, 1); stageH(0, 0, 2); stageH(0, 0, 3);

#define G8_SYNC(WHICH, VMLAST)                                            \
    __builtin_amdgcn_sched_barrier(0);                                    \
    if (more) { stageH(nbuf, knext, WHICH);                               \
                __builtin_amdgcn_sched_barrier(0);                        \
                __builtin_amdgcn_s_waitcnt(0x0F76); /* vmcnt(6) */        \
    } else   { __builtin_amdgcn_s_waitcnt(VMLAST); }                      \
    __builtin_amdgcn_s_barrier();                                         \
    __builtin_amdgcn_sched_barrier(0);

#define G8_COMPUTE(QM, QN, LOADA)                                         \
    if (LOADA) {                                                          \
        _Pragma("unroll") for (int kk = 0; kk < 2; kk++)                  \
        _Pragma("unroll") for (int i = 0; i < 4; i++)                     \
            af[kk][i] = *reinterpret_cast<const short8*>(                 \
                &Al[buf][(QM) * 8192 + (rlA + i * 16) * 64 +              \
                         (((kk << 2) | quad) ^ sw) * 8]);                 \
    }                                                                     \
    _Pragma("unroll") for (int kk = 0; kk < 2; kk++)                      \
    _Pragma("unroll") for (int j = 0; j < 2; j++)                         \
        bfr[kk][j] = *reinterpret_cast<const short8*>(                    \
            &Bl[buf][(QN) * 8192 + (rlB + j * 16) * 64 +                  \
                     (((kk << 2) | quad) ^ sw) * 8]);                     \
    __builtin_amdgcn_s_setprio(1);                                        \
    _Pragma("unroll") for (int kk = 0; kk < 2; kk++)                      \
    _Pragma("unroll") for (int i = 0; i < 4; i++)                         \
    _Pragma("unroll") for (int j = 0; j < 2; j++)                         \
        acc[(QM) * 4 + i][(QN) * 2 + j] =                                 \
            __builtin_amdgcn_mfma_f32_16x16x32_bf16(                      \
                as_bf(af[kk][i]), as_bf(bfr[kk][j]),                      \
                acc[(QM) * 4 + i][(QN) * 2 + j], 0, 0, 0);                \
    __builtin_amdgcn_s_setprio(0);

    for (int t = 0; t < nt; ++t) {
        const int buf = t & 1, nbuf = buf ^ 1;
        const int knext = (t + 1) << 6;
        const bool more = (t + 1 < nt);
        short8 af[2][4], bfr[2][2];
        G8_SYNC(0, 0x0F74)  G8_COMPUTE(0, 0, true)    // needs A0,B0
        G8_SYNC(1, 0x0F72)  G8_COMPUTE(0, 1, false)   // needs B1 (A0 cached)
        G8_SYNC(2, 0x0F70)  G8_COMPUTE(1, 0, true)    // needs A1
        G8_SYNC(3, 0x0F70)  G8_COMPUTE(1, 1, false)   // all
    }
#undef G8_SYNC
#undef G8_COMPUTE

    // epilogue: C/D col=l16 (n), row=quad*4+r (m)
#pragma unroll
    for (int jg = 0; jg < 4; jg++) {
        int cg = n0 + wn + jg * 16 + l16;
        float bv = biasg ? biasg[cg] : 0.f;
#pragma unroll
        for (int ig = 0; ig < 8; ig++) {
#pragma unroll
            for (int r = 0; r < 4; r++) {
                int rg = m0 + wm + ig * 16 + quad * 4 + r;
                float v = acc[ig][jg][r] + bv;
                if (do_gelu) v = gelu_f(v);
                size_t dst;
                if (mode == 1) {
                    int which = cg >> 10, wr2 = cg & 1023;
                    int h = wr2 >> 6, dk = wr2 & 63;
                    int b = rg >> 10, s = rg & 1023;
                    dst = (size_t)which * ((size_t)ROWS * Dc)
                        + (((size_t)b * Hc + h) * Sc_ + s) * DKc + dk;
                } else dst = (size_t)rg * N + cg;
                if constexpr (sizeof(OutT) == 4) outg[dst] = v;
                else                             outg[dst] = f2bf(v);
            }
        }
    }
}

// ---- Attention: register flash, defer-max, LDS-staged K/V (glds double-buffer) ----
__global__ __launch_bounds__(256, 4) void attn_kernel(
    const ushort* __restrict__ Qg, const ushort* __restrict__ Kg,
    const ushort* __restrict__ Vt, const float* __restrict__ relg,
    ushort* __restrict__ ctxg) {
    __shared__ ushort Kl[2][2048];   // 32 rows x 64 elem (128B), chunk-swizzled
    __shared__ ushort Vl[2][2048];   // 64 rows x 32 elem (64B),  chunk-swizzled
    __shared__ float Tpad[1088];     // bias[j] = tab[clamp(j - qb, 0, 126)]
    constexpr float L2E = 1.44269504f;

    const int blk = blockIdx.x;
    const int vb = (blk & 7) * 128 + (blk >> 3);
    const int bh = vb >> 4;            // [0,64)
    const int qblk = vb & 15;          // [0,16)
    const int h = bh & (Hc - 1);
    const int b = bh >> 4;
    const int qb = qblk * 64;
    const int tid = threadIdx.x;
    const int wave = tid >> 6, lane = tid & 63;
    const int quad = lane >> 4, l16 = lane & 15;
    const int ql = wave * 16 + l16;    // block-relative q row of this lane

    const ushort* Kbh  = Kg + (size_t)bh * Sc_ * DKc;
    const ushort* Vtbh = Vt + (size_t)bh * DKc * Sc_;

    auto stage = [&](int buf, int t0) {
        {   // K: slot (r, ch) <- global chunk (r, ch ^ (r&7))
            int r = tid >> 3, ch = tid & 7;
            const ushort* src = Kbh + (size_t)(t0 + r) * DKc + ((ch ^ (r & 7)) * 8);
            async_copy16(&Kl[buf][tid * 8], src);
        }
        {   // V: slot (d, ch) <- global chunk (d, ch ^ ((d>>1)&3))
            int d = tid >> 2, ch = tid & 3;
            const ushort* src = Vtbh + (size_t)d * Sc_ + t0 + ((ch ^ ((d >> 1) & 3)) * 8);
            async_copy16(&Vl[buf][tid * 8], src);
        }
    };

    stage(0, 0);   // prologue (drained by the __syncthreads below)

    for (int j = tid; j < 1087; j += 256) {
        int r = min(max(j - qb, 0), 126);
        Tpad[j] = relg[r * Hc + h];
    }

    short8 aQ[2];
    {
        const ushort* qrow = Qg + ((size_t)bh * Sc_ + qb + ql) * DKc + quad * 8;
#pragma unroll
        for (int f = 0; f < 2; f++) {
            short8 v = *reinterpret_cast<const short8*>(qrow + f * 32);
#pragma unroll
            for (int e = 0; e < 8; e++) v[e] = (short)f2bf(bf2f((ushort)v[e]) * 0.125f);
            aQ[f] = v;
        }
    }
    __syncthreads();   // Tpad + prologue stage complete

    float4v accO[4];
#pragma unroll
    for (int i = 0; i < 4; i++) accO[i] = float4v{0.f, 0.f, 0.f, 0.f};
    float m = -1e30f, lsum = 0.f;
    float ml2 = m * L2E;
    const int srcA = ((quad & 1) * 2) * 16 + l16;
    const int srcB = srcA + 16;
    const bool hi = quad >= 2;

    auto compute = [&](int buf, int t0) {
        short8 vf[4];
#pragma unroll
        for (int dt = 0; dt < 4; dt++) {
            int d = dt * 16 + l16;
            vf[dt] = *reinterpret_cast<const short8*>(
                &Vl[buf][d * 32 + ((quad ^ ((l16 >> 1) & 3)) * 8)]);
        }
        short8 kf[2][2];
#pragma unroll
        for (int kt = 0; kt < 2; kt++)
#pragma unroll
            for (int f = 0; f < 2; f++)
                kf[kt][f] = *reinterpret_cast<const short8*>(
                    &Kl[buf][(kt * 16 + l16) * 64 + (((f * 4 + quad) ^ (l16 & 7)) * 8)]);

        const int jb = t0 + quad * 4 - ql + 63;
        float4v c0 = { Tpad[jb],      Tpad[jb + 1],  Tpad[jb + 2],  Tpad[jb + 3]  };
        float4v c1 = { Tpad[jb + 16], Tpad[jb + 17], Tpad[jb + 18], Tpad[jb + 19] };

        float4v s0 = __builtin_amdgcn_mfma_f32_16x16x32_bf16(as_bf(kf[0][0]), as_bf(aQ[0]), c0, 0, 0, 0);
        s0 = __builtin_amdgcn_mfma_f32_16x16x32_bf16(as_bf(kf[0][1]), as_bf(aQ[1]), s0, 0, 0, 0);
        float4v s1 = __builtin_amdgcn_mfma_f32_16x16x32_bf16(as_bf(kf[1][0]), as_bf(aQ[0]), c1, 0, 0, 0);
        s1 = __builtin_amdgcn_mfma_f32_16x16x32_bf16(as_bf(kf[1][1]), as_bf(aQ[1]), s1, 0, 0, 0);

        float lt = fmaxf(fmaxf(fmaxf(s0[0], s0[1]), fmaxf(s0[2], s0[3])),
                         fmaxf(fmaxf(s1[0], s1[1]), fmaxf(s1[2], s1[3])));
        if (!__all(lt <= m + 8.f)) {
            float tmax = fmaxf(lt, __shfl_xor(lt, 16));
            tmax = fmaxf(tmax, __shfl_xor(tmax, 32));
            float mn = fmaxf(m, tmax);
            float sc = exp2_hw((m - mn) * L2E);
            m = mn; ml2 = m * L2E;
            lsum *= sc;
#pragma unroll
            for (int dt = 0; dt < 4; dt++)
#pragma unroll
                for (int r = 0; r < 4; r++) accO[dt][r] *= sc;
        }
        float p0[4], p1[4];
#pragma unroll
        for (int r = 0; r < 4; r++) {
            p0[r] = exp2_hw(fmaf(s0[r], L2E, -ml2));
            p1[r] = exp2_hw(fmaf(s1[r], L2E, -ml2));
        }
        lsum += ((p0[0] + p0[1]) + (p0[2] + p0[3]))
              + ((p1[0] + p1[1]) + (p1[2] + p1[3]));

        uint w0 = cvt_pk_bf16(p0[0], p0[1]);
        uint w1 = cvt_pk_bf16(p0[2], p0[3]);
        uint w2 = cvt_pk_bf16(p1[0], p1[1]);
        uint w3 = cvt_pk_bf16(p1[2], p1[3]);
        uint a0 = __shfl(w0, srcA), a1 = __shfl(w1, srcA);
        uint a2 = __shfl(w2, srcA), a3 = __shfl(w3, srcA);
        uint b0 = __shfl(w0, srcB), b1 = __shfl(w1, srcB);
        uint b2 = __shfl(w2, srcB), b3 = __shfl(w3, srcB);
        union { uint u[4]; short8 s; } pf;
        pf.u[0] = hi ? a2 : a0;
        pf.u[1] = hi ? a3 : a1;
        pf.u[2] = hi ? b2 : b0;
        pf.u[3] = hi ? b3 : b1;

#pragma unroll
        for (int dt = 0; dt < 4; dt++)
            accO[dt] = __builtin_amdgcn_mfma_f32_16x16x32_bf16(as_bf(vf[dt]), as_bf(pf.s), accO[dt], 0, 0, 0);
    };

    for (int t0 = 0; t0 < Sc_; t0 += 64) {
        __builtin_amdgcn_sched_barrier(0);
        __builtin_amdgcn_s_waitcnt(0x0F70);   // vmcnt(0): stage(buf0) done
        __builtin_amdgcn_s_barrier();
        __builtin_amdgcn_sched_barrier(0);
        stage(1, t0 + 32);
        __builtin_amdgcn_sched_barrier(0);
        compute(0, t0);

        __builtin_amdgcn_sched_barrier(0);
        __builtin_amdgcn_s_waitcnt(0x0F70);   // vmcnt(0): stage(buf1) done
        __builtin_amdgcn_s_barrier();
        __builtin_amdgcn_sched_barrier(0);
        if (t0 + 64 < Sc_) stage(0, t0 + 64);
        __builtin_amdgcn_sched_barrier(0);
        compute(1, t0 + 32);
    }

    lsum += __shfl_xor(lsum, 16);
    lsum += __shfl_xor(lsum, 32);
    float linv = 1.f / lsum;

    const int s = qb + ql;
    ushort* orow = ctxg + ((size_t)b * Sc_ + s) * Dc + h * DKc + quad * 4;
#pragma unroll
    for (int dt = 0; dt < 4; dt++) {
        uint2v o;
        o[0] = cvt_pk_bf16(accO[dt][0] * linv, accO[dt][1] * linv);
        o[1] = cvt_pk_bf16(accO[dt][2] * linv, accO[dt][3] * linv);
        *reinterpret_cast<uint2v*>(orow + dt * 16) = o;
    }
}

extern "C" void kernel_launch(void* const* d_in, const int* in_sizes, int n_in,
                              void* d_out, int out_size, void* d_ws, size_t ws_size,
                              hipStream_t stream) {
    float* out = (float*)d_out;

    static const int exp_sizes[22] = {
        4194304, 1048576, 1024, 1048576, 1024, 1048576, 1024, 1048576, 1024,
        2032, 1024, 1024, 1024, 1024, 4194304, 4096, 4194304, 1024,
        1048576, 1024, 1024, 1024};
    bool ok = (n_in == 22);
    if (ok) for (int i = 0; i < 22; i++) if (in_sizes[i] != exp_sizes[i]) { ok = false; break; }
    if (!ok) {
        sentinel_kernel<<<(out_size + 255) / 256, 256, 0, stream>>>(out, out_size);
        return;
    }

    const float* x   = (const float*)d_in[0];
    const float* wq  = (const float*)d_in[1];  const float* bq  = (const float*)d_in[2];
    const float* wk  = (const float*)d_in[3];  const float* bk  = (const float*)d_in[4];
    const float* wv  = (const float*)d_in[5];  const float* bv  = (const float*)d_in[6];
    const float* wo  = (const float*)d_in[7];  const float* bo  = (const float*)d_in[8];
    const float* rel = (const float*)d_in[9];
    const float* g1  = (const float*)d_in[10]; const float* be1 = (const float*)d_in[11];
    const float* g2  = (const float*)d_in[12]; const float* be2 = (const float*)d_in[13];
    const float* w1  = (const float*)d_in[14]; const float* b1  = (const float*)d_in[15];
    const float* w2  = (const float*)d_in[16]; const float* b2  = (const float*)d_in[17];
    const float* w3  = (const float*)d_in[18]; const float* b3  = (const float*)d_in[19];
    const float* gf  = (const float*)d_in[20]; const float* bfp = (const float*)d_in[21];

    // ws (64 MiB = 8*NE shorts): [0]=Wts [1]=nx/ctx/yb [2]=Qb/x1 [3]=Kb/nx2/ly
    // [4]=Vb [5]=Vt [4..7]=hb (FF phase); bqkv floats at [6] (QKV phase only)
    constexpr size_t NE = (size_t)ROWS * Dc;   // 4M elements
    ushort* base = (ushort*)d_ws;
    ushort* Wts  = base;
    ushort* nx   = base + NE;
    ushort* Qb   = base + 2 * NE;              // Kb=Qb+NE, Vb=Qb+2NE contiguous
    ushort* Kb   = base + 3 * NE;
    ushort* Vb   = base + 4 * NE;
    ushort* Vt   = base + 5 * NE;
    float*  bqkv = (float*)(base + 6 * NE);
    ushort* ctx  = nx;
    ushort* x1   = Qb;
    ushort* nx2  = Kb;
    ushort* hb   = base + 4 * NE;              // 4NE shorts = 32MB
    ushort* yb   = nx;
    ushort* ly   = Kb;

    dim3 blk(256);
    dim3 blk8(512);
    dim3 gQKV(ROWS / 64, 3072 / 128);   // (64, 24) m-fast 3-buf
    dim3 gD(ROWS / 64, Dc / 128);       // (64, 8)  m-fast 3-buf
    dim3 gFF(DFFc / 256, ROWS / 256);   // (16, 16) 256x256 8-phase
    dim3 cD(Dc / 64, Dc / 64);
    dim3 c1(DFFc / 64, Dc / 64);
    dim3 c2(Dc / 64, DFFc / 64);
    dim3 cV(Sc_ / 64, Bc * Hc);

    ln_kernel<true><<<ROWS, blk, 0, stream>>>(x, g1, be1, nx);
    wconv_kernel<<<cD, blk, 0, stream>>>(wq, Wts, Dc, Dc);
    wconv_kernel<<<cD, blk, 0, stream>>>(wk, Wts + (size_t)1024 * 1024, Dc, Dc);
    wconv_kernel<<<cD, blk, 0, stream>>>(wv, Wts + (size_t)2048 * 1024, Dc, Dc);
    bias3_kernel<<<12, blk, 0, stream>>>(bq, bk, bv, bqkv);
    gemm_bt<64, 128, ushort><<<gQKV, blk, 0, stream>>>(nx, Wts, bqkv, nullptr, nullptr, nullptr, Qb, ROWS, 3072, Dc, 0, 1);
    vconv_kernel<<<cV, blk, 0, stream>>>(Vb, Vt);
    attn_kernel<<<dim3(1024), blk, 0, stream>>>(Qb, Kb, Vt, rel, ctx);
    wconv_kernel<<<cD, blk, 0, stream>>>(wo, Wts, Dc, Dc);
    gemm_bt<64, 128, ushort><<<gD, blk, 0, stream>>>(ctx, Wts, bo, x, nullptr, nullptr, x1, ROWS, Dc, Dc, 0, 0);
    ln_kernel<false><<<ROWS, blk, 0, stream>>>(x1, g2, be2, nx2);
    wconv_kernel<<<c1, blk, 0, stream>>>(w1, Wts, Dc, DFFc);
    gemm8_bt<ushort><<<gFF, blk8, 0, stream>>>(nx2, Wts, b1, hb, DFFc, Dc, 1, 0);
    wconv_kernel<<<c2, blk, 0, stream>>>(w2, Wts, DFFc, Dc);
    gemm_bt<64, 128, ushort><<<gD, blk, 0, stream>>>(hb, Wts, b2, nullptr, nx2, nullptr, yb, ROWS, Dc, DFFc, 0, 0);
    ln_kernel<false><<<ROWS, blk, 0, stream>>>(yb, gf, bfp, ly);
    wconv_kernel<<<cD, blk, 0, stream>>>(w3, Wts, Dc, Dc);
    gemm_bt<64, 128, float><<<gD, blk, 0, stream>>>(ly, Wts, b3, nullptr, x1, yb, out, ROWS, Dc, Dc, 0, 0);
}

// Round 8
// 406.779 us; speedup vs baseline: 1.1097x; 1.0865x over previous
//
#include <hip/hip_runtime.h>
#include <hip/hip_bf16.h>
#include <math.h>

// TransformerBlock B=4,S=1024,D=1024,H=16,DK=64,DFF=4096. Externals f32, out f32.
// GEMM engines:
//  - gemm_bt<BM,BN,BK>: 3-buffer counted-vmcnt pipeline, m-fast grid (XCD=m%8).
//    BK=32 (QKV: keeps 4 blocks/CU) or BK=64 (proj/FF2/out: halves barrier count,
//    16 MFMA/wave/iter, full 8-chunk XOR swizzle both-sides -> conflict-free).
//  - gemm8_bt: 8-phase 256x256 (FF1); epilogue reordered row-outer so each 128B
//    output line is completed by 4 back-to-back stores (kills write-allocate
//    inflation: WRITE was 2.4x ideal).
// wq/wk/wv/wo converted in ONE up-front launch (wo packed at Wts+3M).
// Attention: register flash, defer-max, LDS-staged K/V glds double-buffer.

constexpr int Bc = 4, Sc_ = 1024, Dc = 1024, Hc = 16, DKc = 64, DFFc = 4096;
constexpr int ROWS = Bc * Sc_;   // 4096

typedef short short8 __attribute__((ext_vector_type(8)));
typedef __bf16 bf16x8 __attribute__((ext_vector_type(8)));
typedef float float4v __attribute__((ext_vector_type(4)));
typedef uint uint2v __attribute__((ext_vector_type(2)));

__device__ __forceinline__ float bf2f(ushort u) {
    union { uint i; float f; } v; v.i = ((uint)u) << 16; return v.f;
}
__device__ __forceinline__ ushort f2bf(float f) {
    union { float f; uint i; } v; v.f = f;
    uint r = v.i + 0x7FFF + ((v.i >> 16) & 1);   // RNE
    return (ushort)(r >> 16);
}
__device__ __forceinline__ bf16x8 as_bf(short8 s) {
    union { short8 s; bf16x8 b; } u; u.s = s; return u.b;
}
__device__ __forceinline__ uint cvt_pk_bf16(float lo, float hi) {
    uint r;
    asm("v_cvt_pk_bf16_f32 %0, %1, %2" : "=v"(r) : "v"(lo), "v"(hi));
    return r;
}
__device__ __forceinline__ float exp2_hw(float x) {   // v_exp_f32: 2^x, ~1 ulp
    float r;
    asm("v_exp_f32 %0, %1" : "=v"(r) : "v"(x));
    return r;
}
__device__ __forceinline__ void async_copy16(void* lds, const void* g) {
    __builtin_amdgcn_global_load_lds((const __attribute__((address_space(1))) uint*)g,
                                     (__attribute__((address_space(3))) uint*)lds, 16, 0, 0);
}
// exact-GELU via Abramowitz-Stegun erf (max abs err 1.5e-7)
__device__ __forceinline__ float gelu_f(float v) {
    float z = v * 0.70710678118654752f;
    float az = fabsf(z);
    float t = 1.f / (1.f + 0.3275911f * az);
    float p = ((((1.061405429f * t - 1.453152027f) * t) + 1.421413741f) * t
               - 0.284496736f) * t + 0.254829592f;
    float y = 1.f - p * t * __expf(-az * az);
    float er = (z < 0.f) ? -y : y;
    return 0.5f * v * (1.f + er);
}

__global__ void sentinel_kernel(float* __restrict__ out, int n) {
    int i = blockIdx.x * 256 + threadIdx.x;
    if (i < n) out[i] = 100.0f;
}

// combined qkv bias
__global__ void bias3_kernel(const float* __restrict__ a, const float* __restrict__ b,
                             const float* __restrict__ c, float* __restrict__ o) {
    int i = blockIdx.x * 256 + threadIdx.x;
    if (i < 1024) o[i] = a[i];
    else if (i < 2048) o[i] = b[i - 1024];
    else if (i < 3072) o[i] = c[i - 2048];
}

// ---- transpose+convert: W[K][N] f32 -> Wt[N][K] bf16, 64x64 tiles ----
__global__ __launch_bounds__(256) void wconv_kernel(const float* __restrict__ W,
                                                    ushort* __restrict__ Wt,
                                                    int K, int N) {
    __shared__ float T[64][65];
    const int kt = blockIdx.y * 64, nt = blockIdx.x * 64;
    const int tid = threadIdx.x;
#pragma unroll
    for (int it = 0; it < 4; it++) {
        int r = it * 16 + (tid >> 4), c = (tid & 15) * 4;
        float4v v = *reinterpret_cast<const float4v*>(W + (size_t)(kt + r) * N + nt + c);
        T[r][c] = v[0]; T[r][c + 1] = v[1]; T[r][c + 2] = v[2]; T[r][c + 3] = v[3];
    }
    __syncthreads();
    int n = tid >> 2, kc = (tid & 3) * 16;
    short8 a, b;
#pragma unroll
    for (int q = 0; q < 8; q++) {
        a[q] = (short)f2bf(T[kc + q][n]);
        b[q] = (short)f2bf(T[kc + 8 + q][n]);
    }
    ushort* dst = Wt + (size_t)(nt + n) * K + kt + kc;
    *reinterpret_cast<short8*>(dst) = a;
    *reinterpret_cast<short8*>(dst + 8) = b;
}

// ---- fused conversion of four 1024x1024 weights (wq,wk,wv,wo) ----
__global__ __launch_bounds__(256) void wconv4_kernel(
    const float* __restrict__ w0, const float* __restrict__ w1,
    const float* __restrict__ w2, const float* __restrict__ w3,
    ushort* __restrict__ o) {
    __shared__ float T[64][65];
    const int z = blockIdx.z;
    const float* W = (z == 0) ? w0 : (z == 1) ? w1 : (z == 2) ? w2 : w3;
    ushort* Wt = o + (size_t)z * 1024 * 1024;
    const int kt = blockIdx.y * 64, nt = blockIdx.x * 64;
    const int tid = threadIdx.x;
#pragma unroll
    for (int it = 0; it < 4; it++) {
        int r = it * 16 + (tid >> 4), c = (tid & 15) * 4;
        float4v v = *reinterpret_cast<const float4v*>(W + (size_t)(kt + r) * 1024 + nt + c);
        T[r][c] = v[0]; T[r][c + 1] = v[1]; T[r][c + 2] = v[2]; T[r][c + 3] = v[3];
    }
    __syncthreads();
    int n = tid >> 2, kc = (tid & 3) * 16;
    short8 a, b;
#pragma unroll
    for (int q = 0; q < 8; q++) {
        a[q] = (short)f2bf(T[kc + q][n]);
        b[q] = (short)f2bf(T[kc + 8 + q][n]);
    }
    ushort* dst = Wt + (size_t)(nt + n) * 1024 + kt + kc;
    *reinterpret_cast<short8*>(dst) = a;
    *reinterpret_cast<short8*>(dst + 8) = b;
}

// ---- V transpose: V[b,h,s,dk] bf16 -> Vt[b,h,dk,s] bf16 ----
__global__ __launch_bounds__(256) void vconv_kernel(const ushort* __restrict__ V,
                                                    ushort* __restrict__ Vt) {
    __shared__ ushort T[64][65];
    const int bh = blockIdx.y;
    const int s0 = blockIdx.x * 64;
    const int tid = threadIdx.x;
    const int r = tid >> 2, c = (tid & 3) * 16;
    const ushort* src = V + ((size_t)bh * Sc_ + s0 + r) * DKc + c;
    short8 a = *reinterpret_cast<const short8*>(src);
    short8 b = *reinterpret_cast<const short8*>(src + 8);
#pragma unroll
    for (int q = 0; q < 8; q++) { T[r][c + q] = (ushort)a[q]; T[r][c + 8 + q] = (ushort)b[q]; }
    __syncthreads();
    const int dk = tid >> 2, sc2 = (tid & 3) * 16;
    short8 o0, o1;
#pragma unroll
    for (int q = 0; q < 8; q++) { o0[q] = (short)T[sc2 + q][dk]; o1[q] = (short)T[sc2 + 8 + q][dk]; }
    ushort* dst = Vt + ((size_t)bh * DKc + dk) * Sc_ + s0 + sc2;
    *reinterpret_cast<short8*>(dst) = o0;
    *reinterpret_cast<short8*>(dst + 8) = o1;
}

// ---- LayerNorm: one block per row of D=1024 ----
template<bool IN_F32>
__global__ __launch_bounds__(256) void ln_kernel(const void* __restrict__ xin,
                                                 const float* __restrict__ g,
                                                 const float* __restrict__ be,
                                                 ushort* __restrict__ out) {
    int row = blockIdx.x;
    int tid = threadIdx.x;
    float v0[4], s = 0.f, ss = 0.f;
#pragma unroll
    for (int i = 0; i < 4; i++) {
        int c = tid + i * 256;
        float f = IN_F32 ? ((const float*)xin)[(size_t)row * Dc + c]
                         : bf2f(((const ushort*)xin)[(size_t)row * Dc + c]);
        v0[i] = f; s += f; ss += f * f;
    }
#pragma unroll
    for (int off = 32; off > 0; off >>= 1) {
        s += __shfl_down(s, off);
        ss += __shfl_down(ss, off);
    }
    __shared__ float red[8];
    __shared__ float stat[2];
    int wave = tid >> 6, lane = tid & 63;
    if (lane == 0) { red[wave] = s; red[wave + 4] = ss; }
    __syncthreads();
    if (tid == 0) {
        float a = 0.f, b = 0.f;
        for (int w = 0; w < 4; w++) { a += red[w]; b += red[w + 4]; }
        stat[0] = a; stat[1] = b;
    }
    __syncthreads();
    float mean = stat[0] * (1.f / Dc);
    float var  = stat[1] * (1.f / Dc) - mean * mean;
    float inv  = rsqrtf(var + 1e-5f);
#pragma unroll
    for (int i = 0; i < 4; i++) {
        int c = tid + i * 256;
        float nv = (v0[i] - mean) * inv * g[c] + be[c];
        out[(size_t)row * Dc + c] = f2bf(nv);
    }
}

// ---- bt-GEMM, 3-buffer counted-vmcnt pipeline ----
// BK=32: linear chunks (validated). BK=64: 8-chunk XOR swizzle on stage-source
// and ds_read (both sides -> values bit-identical); row stride 128B would be a
// hard bank conflict unswizzled. kk ascending -> K-order identical to BK=32.
template<int BM, int BN, int BKt, typename OutT>
__global__ __launch_bounds__(256) void gemm_bt(
    const ushort* __restrict__ Ag, const ushort* __restrict__ Wt,
    const float* __restrict__ biasg,
    const float* __restrict__ res1f,
    const ushort* __restrict__ resi1, const ushort* __restrict__ resi2,
    OutT* __restrict__ outg,
    int M, int N, int K, int do_gelu, int mode) {
    constexpr int WN = BN / 64;            // waves along n
    constexpr int WM = 4 / WN;             // waves along m
    constexpr int MI = BM / (WM * 16);     // m-frags per wave
    constexpr int KS = BKt / 32;           // K sub-steps per iter
    constexpr int CPR = BKt / 8;           // 16B chunks per row
    constexpr int TSZ = (BM + BN) * BKt;   // shorts per LDS buffer
    constexpr int SLOTS = (BM + BN) * CPR; // 16B chunks per buffer
    constexpr int LPT = SLOTS / 256;       // glds per thread per tile
    constexpr unsigned VM_L = 0x0F70 | (unsigned)LPT;   // vmcnt(LPT)
    __shared__ ushort Tile[3 * TSZ];
    const int tid = threadIdx.x;
    const int wave = tid >> 6, lane = tid & 63;
    const int quad = lane >> 4, l16 = lane & 15;
    const int m0 = blockIdx.x * BM, n0 = blockIdx.y * BN;
    const int wm = (wave / WN) * (MI * 16), wn = (wave % WN) * 64;
    const int sw = l16 & 7;                // read-side swizzle (BK=64 only)

    float4v acc[MI][4];
    const float4v zero = {0.f, 0.f, 0.f, 0.f};
#pragma unroll
    for (int i = 0; i < MI; i++)
#pragma unroll
        for (int j = 0; j < 4; j++) acc[i][j] = zero;

    auto stage = [&](int buf, int k0) {
#pragma unroll
        for (int it = 0; it < LPT; it++) {
            int s = tid + it * 256;
            int r = s / CPR, pch = s % CPR;
            int ch = (BKt == 64) ? (pch ^ (r & 7)) : pch;
            const ushort* src = (r < BM)
                ? Ag + (size_t)(m0 + r) * K + k0 + ch * 8
                : Wt + (size_t)(n0 + r - BM) * K + k0 + ch * 8;
            async_copy16(&Tile[buf * TSZ + s * 8], src);
        }
    };

    const int nit = K / BKt;
    stage(0, 0);
    stage(1, BKt);
    int bc = 0, bs = 2;                    // compute buf, stage buf = (i+2)%3
    for (int i = 0; i < nit; i++) {
        __builtin_amdgcn_sched_barrier(0);
        if (i + 1 < nit) __builtin_amdgcn_s_waitcnt(VM_L);      // tile i done
        else             __builtin_amdgcn_s_waitcnt(0x0F70);    // last: drain
        __builtin_amdgcn_s_barrier();
        __builtin_amdgcn_sched_barrier(0);
        if (i + 2 < nit) stage(bs, (i + 2) * BKt);   // overlaps compute below
        const ushort* Asb = &Tile[bc * TSZ];
        const ushort* Bsb = &Tile[bc * TSZ + BM * BKt];
        short8 af[KS][MI], bfr[KS][4];
#pragma unroll
        for (int kk = 0; kk < KS; kk++) {
#pragma unroll
            for (int ii = 0; ii < MI; ii++) {
                int ch = (BKt == 64) ? (((kk << 2) | quad) ^ sw) : quad;
                af[kk][ii] = *reinterpret_cast<const short8*>(
                    &Asb[(wm + ii * 16 + l16) * BKt + ch * 8]);
            }
#pragma unroll
            for (int j = 0; j < 4; j++) {
                int ch = (BKt == 64) ? (((kk << 2) | quad) ^ sw) : quad;
                bfr[kk][j] = *reinterpret_cast<const short8*>(
                    &Bsb[(wn + j * 16 + l16) * BKt + ch * 8]);
            }
        }
#pragma unroll
        for (int kk = 0; kk < KS; kk++)
#pragma unroll
            for (int j = 0; j < 4; j++)
#pragma unroll
                for (int ii = 0; ii < MI; ii++)
                    acc[ii][j] = __builtin_amdgcn_mfma_f32_16x16x32_bf16(
                        as_bf(af[kk][ii]), as_bf(bfr[kk][j]), acc[ii][j], 0, 0, 0);
        bc = (bc == 2) ? 0 : bc + 1;
        bs = (bs == 2) ? 0 : bs + 1;
    }
    __builtin_amdgcn_s_barrier();

    // epilogue: C/D layout col=lane&15, row=quad*4+reg; row-outer (line-merged)
    float bvv[4];
#pragma unroll
    for (int j = 0; j < 4; j++) bvv[j] = biasg ? biasg[n0 + wn + j * 16 + l16] : 0.f;
#pragma unroll
    for (int i = 0; i < MI; i++) {
#pragma unroll
        for (int r = 0; r < 4; r++) {
            int rg = m0 + wm + i * 16 + quad * 4 + r;
#pragma unroll
            for (int j = 0; j < 4; j++) {
                int cg = n0 + wn + j * 16 + l16;
                float v = acc[i][j][r] + bvv[j];
                if (do_gelu) v = gelu_f(v);
                size_t idx = (size_t)rg * N + cg;
                if (res1f) v += res1f[idx];
                if (resi1) v += bf2f(resi1[idx]);
                if (resi2) v += bf2f(resi2[idx]);
                size_t dst;
                if (mode == 1) {   // fused QKV: cg in [0,3072)
                    int which = cg >> 10, wr2 = cg & 1023;
                    int h = wr2 >> 6, dk = wr2 & 63;
                    int b = rg >> 10, s = rg & 1023;
                    dst = (size_t)which * ((size_t)ROWS * Dc)
                        + (((size_t)b * Hc + h) * Sc_ + s) * DKc + dk;
                } else dst = idx;
                if constexpr (sizeof(OutT) == 4) outg[dst] = v;
                else                             outg[dst] = f2bf(v);
            }
        }
    }
}

// ---- gemm8_bt: 8-phase 256x256, BK=64, 512 threads (FF1) ----
template<typename OutT>
__global__ __launch_bounds__(512, 2) void gemm8_bt(
    const ushort* __restrict__ Ag, const ushort* __restrict__ Wt,
    const float* __restrict__ biasg, OutT* __restrict__ outg,
    int N, int K, int do_gelu, int mode) {
    __shared__ ushort Al[2][16384];   // [buf][half*8192 + rl*64 + pch*8]
    __shared__ ushort Bl[2][16384];
    const int tid = threadIdx.x;
    const int wave = tid >> 6, lane = tid & 63;
    const int quad = lane >> 4, l16 = lane & 15;
    const int wm = (wave >> 2) * 128, wn = (wave & 3) * 64;
    const int m0 = blockIdx.y * 256, n0 = blockIdx.x * 256;

    float4v acc[8][4];
    const float4v zero = {0.f, 0.f, 0.f, 0.f};
#pragma unroll
    for (int i = 0; i < 8; i++)
#pragma unroll
        for (int j = 0; j < 4; j++) acc[i][j] = zero;

    auto stageH = [&](int buf, int k0, int which) {
#pragma unroll
        for (int it = 0; it < 2; it++) {
            int s = tid + it * 512;            // slot 0..1023
            int rl = s >> 3, pch = s & 7;
            int ch = pch ^ (rl & 7);           // pre-swizzled source chunk
            const ushort* src; ushort* dst;
            if (which == 0)      { int row = ((rl >> 6) << 7) + (rl & 63);
                                   src = Ag + (size_t)(m0 + row) * K + k0 + ch * 8;
                                   dst = &Al[buf][s * 8]; }
            else if (which == 1) { int row = ((rl >> 5) << 6) + (rl & 31);
                                   src = Wt + (size_t)(n0 + row) * K + k0 + ch * 8;
                                   dst = &Bl[buf][s * 8]; }
            else if (which == 2) { int row = ((rl >> 5) << 6) + 32 + (rl & 31);
                                   src = Wt + (size_t)(n0 + row) * K + k0 + ch * 8;
                                   dst = &Bl[buf][8192 + s * 8]; }
            else                 { int row = ((rl >> 6) << 7) + 64 + (rl & 63);
                                   src = Ag + (size_t)(m0 + row) * K + k0 + ch * 8;
                                   dst = &Al[buf][8192 + s * 8]; }
            async_copy16(dst, src);
        }
    };

    const int rlA = ((wm >> 7) << 6) + l16;   // row-within-half base for A reads
    const int rlB = ((wn >> 6) << 5) + l16;   // for B reads
    const int sw  = l16 & 7;                  // read-side swizzle (== rl&7)

    const int nt = K >> 6;                    // K/64 tiles
    stageH(0, 0, 0); stageH(0, 0, 1); stageH(0, 0, 2); stageH(0, 0, 3);

#define G8_SYNC(WHICH, VMLAST)                                            \
    __builtin_amdgcn_sched_barrier(0);                                    \
    if (more) { stageH(nbuf, knext, WHICH);                               \
                __builtin_amdgcn_sched_barrier(0);                        \
                __builtin_amdgcn_s_waitcnt(0x0F76); /* vmcnt(6) */        \
    } else   { __builtin_amdgcn_s_waitcnt(VMLAST); }                      \
    __builtin_amdgcn_s_barrier();                                         \
    __builtin_amdgcn_sched_barrier(0);

#define G8_COMPUTE(QM, QN, LOADA)                                         \
    if (LOADA) {                                                          \
        _Pragma("unroll") for (int kk = 0; kk < 2; kk++)                  \
        _Pragma("unroll") for (int i = 0; i < 4; i++)                     \
            af[kk][i] = *reinterpret_cast<const short8*>(                 \
                &Al[buf][(QM) * 8192 + (rlA + i * 16) * 64 +              \
                         (((kk << 2) | quad) ^ sw) * 8]);                 \
    }                                                                     \
    _Pragma("unroll") for (int kk = 0; kk < 2; kk++)                      \
    _Pragma("unroll") for (int j = 0; j < 2; j++)                         \
        bfr[kk][j] = *reinterpret_cast<const short8*>(                    \
            &Bl[buf][(QN) * 8192 + (rlB + j * 16) * 64 +                  \
                     (((kk << 2) | quad) ^ sw) * 8]);                     \
    __builtin_amdgcn_s_setprio(1);                                        \
    _Pragma("unroll") for (int kk = 0; kk < 2; kk++)                      \
    _Pragma("unroll") for (int i = 0; i < 4; i++)                         \
    _Pragma("unroll") for (int j = 0; j < 2; j++)                         \
        acc[(QM) * 4 + i][(QN) * 2 + j] =                                 \
            __builtin_amdgcn_mfma_f32_16x16x32_bf16(                      \
                as_bf(af[kk][i]), as_bf(bfr[kk][j]),                      \
                acc[(QM) * 4 + i][(QN) * 2 + j], 0, 0, 0);                \
    __builtin_amdgcn_s_setprio(0);

    for (int t = 0; t < nt; ++t) {
        const int buf = t & 1, nbuf = buf ^ 1;
        const int knext = (t + 1) << 6;
        const bool more = (t + 1 < nt);
        short8 af[2][4], bfr[2][2];
        G8_SYNC(0, 0x0F74)  G8_COMPUTE(0, 0, true)    // needs A0,B0
        G8_SYNC(1, 0x0F72)  G8_COMPUTE(0, 1, false)   // needs B1 (A0 cached)
        G8_SYNC(2, 0x0F70)  G8_COMPUTE(1, 0, true)    // needs A1
        G8_SYNC(3, 0x0F70)  G8_COMPUTE(1, 1, false)   // all
    }
#undef G8_SYNC
#undef G8_COMPUTE

    // epilogue: row-outer so each 128B output line gets its 4 stores
    // back-to-back (prevents write-allocate partial-line eviction)
    float bvv[4];
#pragma unroll
    for (int jg = 0; jg < 4; jg++) bvv[jg] = biasg ? biasg[n0 + wn + jg * 16 + l16] : 0.f;
#pragma unroll
    for (int ig = 0; ig < 8; ig++) {
#pragma unroll
        for (int r = 0; r < 4; r++) {
            int rg = m0 + wm + ig * 16 + quad * 4 + r;
            if (mode == 1) {
#pragma unroll
                for (int jg = 0; jg < 4; jg++) {
                    int cg = n0 + wn + jg * 16 + l16;
                    float v = acc[ig][jg][r] + bvv[jg];
                    if (do_gelu) v = gelu_f(v);
                    int which = cg >> 10, wr2 = cg & 1023;
                    int h = wr2 >> 6, dk = wr2 & 63;
                    int b = rg >> 10, s = rg & 1023;
                    size_t dst = (size_t)which * ((size_t)ROWS * Dc)
                        + (((size_t)b * Hc + h) * Sc_ + s) * DKc + dk;
                    if constexpr (sizeof(OutT) == 4) outg[dst] = v;
                    else                             outg[dst] = f2bf(v);
                }
            } else {
                OutT* orow = outg + (size_t)rg * N + n0 + wn + l16;
#pragma unroll
                for (int jg = 0; jg < 4; jg++) {
                    float v = acc[ig][jg][r] + bvv[jg];
                    if (do_gelu) v = gelu_f(v);
                    if constexpr (sizeof(OutT) == 4) orow[jg * 16] = v;
                    else                             orow[jg * 16] = f2bf(v);
                }
            }
        }
    }
}

// ---- Attention: register flash, defer-max, LDS-staged K/V (glds double-buffer) ----
__global__ __launch_bounds__(256, 4) void attn_kernel(
    const ushort* __restrict__ Qg, const ushort* __restrict__ Kg,
    const ushort* __restrict__ Vt, const float* __restrict__ relg,
    ushort* __restrict__ ctxg) {
    __shared__ ushort Kl[2][2048];   // 32 rows x 64 elem (128B), chunk-swizzled
    __shared__ ushort Vl[2][2048];   // 64 rows x 32 elem (64B),  chunk-swizzled
    __shared__ float Tpad[1088];     // bias[j] = tab[clamp(j - qb, 0, 126)]
    constexpr float L2E = 1.44269504f;

    const int blk = blockIdx.x;
    const int vb = (blk & 7) * 128 + (blk >> 3);
    const int bh = vb >> 4;            // [0,64)
    const int qblk = vb & 15;          // [0,16)
    const int h = bh & (Hc - 1);
    const int b = bh >> 4;
    const int qb = qblk * 64;
    const int tid = threadIdx.x;
    const int wave = tid >> 6, lane = tid & 63;
    const int quad = lane >> 4, l16 = lane & 15;
    const int ql = wave * 16 + l16;    // block-relative q row of this lane

    const ushort* Kbh  = Kg + (size_t)bh * Sc_ * DKc;
    const ushort* Vtbh = Vt + (size_t)bh * DKc * Sc_;

    auto stage = [&](int buf, int t0) {
        {   // K: slot (r, ch) <- global chunk (r, ch ^ (r&7))
            int r = tid >> 3, ch = tid & 7;
            const ushort* src = Kbh + (size_t)(t0 + r) * DKc + ((ch ^ (r & 7)) * 8);
            async_copy16(&Kl[buf][tid * 8], src);
        }
        {   // V: slot (d, ch) <- global chunk (d, ch ^ ((d>>1)&3))
            int d = tid >> 2, ch = tid & 3;
            const ushort* src = Vtbh + (size_t)d * Sc_ + t0 + ((ch ^ ((d >> 1) & 3)) * 8);
            async_copy16(&Vl[buf][tid * 8], src);
        }
    };

    stage(0, 0);   // prologue (drained by the __syncthreads below)

    for (int j = tid; j < 1087; j += 256) {
        int r = min(max(j - qb, 0), 126);
        Tpad[j] = relg[r * Hc + h];
    }

    short8 aQ[2];
    {
        const ushort* qrow = Qg + ((size_t)bh * Sc_ + qb + ql) * DKc + quad * 8;
#pragma unroll
        for (int f = 0; f < 2; f++) {
            short8 v = *reinterpret_cast<const short8*>(qrow + f * 32);
#pragma unroll
            for (int e = 0; e < 8; e++) v[e] = (short)f2bf(bf2f((ushort)v[e]) * 0.125f);
            aQ[f] = v;
        }
    }
    __syncthreads();   // Tpad + prologue stage complete

    float4v accO[4];
#pragma unroll
    for (int i = 0; i < 4; i++) accO[i] = float4v{0.f, 0.f, 0.f, 0.f};
    float m = -1e30f, lsum = 0.f;
    float ml2 = m * L2E;
    const int srcA = ((quad & 1) * 2) * 16 + l16;
    const int srcB = srcA + 16;
    const bool hi = quad >= 2;

    auto compute = [&](int buf, int t0) {
        short8 vf[4];
#pragma unroll
        for (int dt = 0; dt < 4; dt++) {
            int d = dt * 16 + l16;
            vf[dt] = *reinterpret_cast<const short8*>(
                &Vl[buf][d * 32 + ((quad ^ ((l16 >> 1) & 3)) * 8)]);
        }
        short8 kf[2][2];
#pragma unroll
        for (int kt = 0; kt < 2; kt++)
#pragma unroll
            for (int f = 0; f < 2; f++)
                kf[kt][f] = *reinterpret_cast<const short8*>(
                    &Kl[buf][(kt * 16 + l16) * 64 + (((f * 4 + quad) ^ (l16 & 7)) * 8)]);

        const int jb = t0 + quad * 4 - ql + 63;
        float4v c0 = { Tpad[jb],      Tpad[jb + 1],  Tpad[jb + 2],  Tpad[jb + 3]  };
        float4v c1 = { Tpad[jb + 16], Tpad[jb + 17], Tpad[jb + 18], Tpad[jb + 19] };

        float4v s0 = __builtin_amdgcn_mfma_f32_16x16x32_bf16(as_bf(kf[0][0]), as_bf(aQ[0]), c0, 0, 0, 0);
        s0 = __builtin_amdgcn_mfma_f32_16x16x32_bf16(as_bf(kf[0][1]), as_bf(aQ[1]), s0, 0, 0, 0);
        float4v s1 = __builtin_amdgcn_mfma_f32_16x16x32_bf16(as_bf(kf[1][0]), as_bf(aQ[0]), c1, 0, 0, 0);
        s1 = __builtin_amdgcn_mfma_f32_16x16x32_bf16(as_bf(kf[1][1]), as_bf(aQ[1]), s1, 0, 0, 0);

        float lt = fmaxf(fmaxf(fmaxf(s0[0], s0[1]), fmaxf(s0[2], s0[3])),
                         fmaxf(fmaxf(s1[0], s1[1]), fmaxf(s1[2], s1[3])));
        if (!__all(lt <= m + 8.f)) {
            float tmax = fmaxf(lt, __shfl_xor(lt, 16));
            tmax = fmaxf(tmax, __shfl_xor(tmax, 32));
            float mn = fmaxf(m, tmax);
            float sc = exp2_hw((m - mn) * L2E);
            m = mn; ml2 = m * L2E;
            lsum *= sc;
#pragma unroll
            for (int dt = 0; dt < 4; dt++)
#pragma unroll
                for (int r = 0; r < 4; r++) accO[dt][r] *= sc;
        }
        float p0[4], p1[4];
#pragma unroll
        for (int r = 0; r < 4; r++) {
            p0[r] = exp2_hw(fmaf(s0[r], L2E, -ml2));
            p1[r] = exp2_hw(fmaf(s1[r], L2E, -ml2));
        }
        lsum += ((p0[0] + p0[1]) + (p0[2] + p0[3]))
              + ((p1[0] + p1[1]) + (p1[2] + p1[3]));

        uint w0 = cvt_pk_bf16(p0[0], p0[1]);
        uint w1 = cvt_pk_bf16(p0[2], p0[3]);
        uint w2 = cvt_pk_bf16(p1[0], p1[1]);
        uint w3 = cvt_pk_bf16(p1[2], p1[3]);
        uint a0 = __shfl(w0, srcA), a1 = __shfl(w1, srcA);
        uint a2 = __shfl(w2, srcA), a3 = __shfl(w3, srcA);
        uint b0 = __shfl(w0, srcB), b1 = __shfl(w1, srcB);
        uint b2 = __shfl(w2, srcB), b3 = __shfl(w3, srcB);
        union { uint u[4]; short8 s; } pf;
        pf.u[0] = hi ? a2 : a0;
        pf.u[1] = hi ? a3 : a1;
        pf.u[2] = hi ? b2 : b0;
        pf.u[3] = hi ? b3 : b1;

#pragma unroll
        for (int dt = 0; dt < 4; dt++)
            accO[dt] = __builtin_amdgcn_mfma_f32_16x16x32_bf16(as_bf(vf[dt]), as_bf(pf.s), accO[dt], 0, 0, 0);
    };

    for (int t0 = 0; t0 < Sc_; t0 += 64) {
        __builtin_amdgcn_sched_barrier(0);
        __builtin_amdgcn_s_waitcnt(0x0F70);   // vmcnt(0): stage(buf0) done
        __builtin_amdgcn_s_barrier();
        __builtin_amdgcn_sched_barrier(0);
        stage(1, t0 + 32);
        __builtin_amdgcn_sched_barrier(0);
        compute(0, t0);

        __builtin_amdgcn_sched_barrier(0);
        __builtin_amdgcn_s_waitcnt(0x0F70);   // vmcnt(0): stage(buf1) done
        __builtin_amdgcn_s_barrier();
        __builtin_amdgcn_sched_barrier(0);
        if (t0 + 64 < Sc_) stage(0, t0 + 64);
        __builtin_amdgcn_sched_barrier(0);
        compute(1, t0 + 32);
    }

    lsum += __shfl_xor(lsum, 16);
    lsum += __shfl_xor(lsum, 32);
    float linv = 1.f / lsum;

    const int s = qb + ql;
    ushort* orow = ctxg + ((size_t)b * Sc_ + s) * Dc + h * DKc + quad * 4;
#pragma unroll
    for (int dt = 0; dt < 4; dt++) {
        uint2v o;
        o[0] = cvt_pk_bf16(accO[dt][0] * linv, accO[dt][1] * linv);
        o[1] = cvt_pk_bf16(accO[dt][2] * linv, accO[dt][3] * linv);
        *reinterpret_cast<uint2v*>(orow + dt * 16) = o;
    }
}

extern "C" void kernel_launch(void* const* d_in, const int* in_sizes, int n_in,
                              void* d_out, int out_size, void* d_ws, size_t ws_size,
                              hipStream_t stream) {
    float* out = (float*)d_out;

    static const int exp_sizes[22] = {
        4194304, 1048576, 1024, 1048576, 1024, 1048576, 1024, 1048576, 1024,
        2032, 1024, 1024, 1024, 1024, 4194304, 4096, 4194304, 1024,
        1048576, 1024, 1024, 1024};
    bool ok = (n_in == 22);
    if (ok) for (int i = 0; i < 22; i++) if (in_sizes[i] != exp_sizes[i]) { ok = false; break; }
    if (!ok) {
        sentinel_kernel<<<(out_size + 255) / 256, 256, 0, stream>>>(out, out_size);
        return;
    }

    const float* x   = (const float*)d_in[0];
    const float* wq  = (const float*)d_in[1];  const float* bq  = (const float*)d_in[2];
    const float* wk  = (const float*)d_in[3];  const float* bk  = (const float*)d_in[4];
    const float* wv  = (const float*)d_in[5];  const float* bv  = (const float*)d_in[6];
    const float* wo  = (const float*)d_in[7];  const float* bo  = (const float*)d_in[8];
    const float* rel = (const float*)d_in[9];
    const float* g1  = (const float*)d_in[10]; const float* be1 = (const float*)d_in[11];
    const float* g2  = (const float*)d_in[12]; const float* be2 = (const float*)d_in[13];
    const float* w1  = (const float*)d_in[14]; const float* b1  = (const float*)d_in[15];
    const float* w2  = (const float*)d_in[16]; const float* b2  = (const float*)d_in[17];
    const float* w3  = (const float*)d_in[18]; const float* b3  = (const float*)d_in[19];
    const float* gf  = (const float*)d_in[20]; const float* bfp = (const float*)d_in[21];

    // ws (64 MiB = 8*NE shorts): [0]=Wts(wq|wk|wv|wo, later w1/w2/w3)
    // [1]=nx/ctx/yb [2]=Qb/x1 [3]=Kb/nx2/ly [4]=Vb [5]=Vt [4..7]=hb (FF phase);
    // bqkv floats at [6] (QKV phase only)
    constexpr size_t NE = (size_t)ROWS * Dc;   // 4M elements
    ushort* base = (ushort*)d_ws;
    ushort* Wts  = base;
    ushort* nx   = base + NE;
    ushort* Qb   = base + 2 * NE;              // Kb=Qb+NE, Vb=Qb+2NE contiguous
    ushort* Kb   = base + 3 * NE;
    ushort* Vb   = base + 4 * NE;
    ushort* Vt   = base + 5 * NE;
    float*  bqkv = (float*)(base + 6 * NE);
    ushort* ctx  = nx;
    ushort* x1   = Qb;
    ushort* nx2  = Kb;
    ushort* hb   = base + 4 * NE;              // 4NE shorts = 32MB
    ushort* yb   = nx;
    ushort* ly   = Kb;

    dim3 blk(256);
    dim3 blk8(512);
    dim3 gQKV(ROWS / 64, 3072 / 128);   // (64, 24) m-fast, BK=32
    dim3 gD(ROWS / 64, Dc / 128);       // (64, 8)  m-fast, BK=64
    dim3 gFF(DFFc / 256, ROWS / 256);   // (16, 16) 256x256 8-phase
    dim3 c4(16, 16, 4);
    dim3 c1(DFFc / 64, Dc / 64);
    dim3 c2(Dc / 64, DFFc / 64);
    dim3 cD(Dc / 64, Dc / 64);
    dim3 cV(Sc_ / 64, Bc * Hc);

    // up-front: all 1024x1024 weight conversions in one launch + qkv bias
    wconv4_kernel<<<c4, blk, 0, stream>>>(wq, wk, wv, wo, Wts);
    bias3_kernel<<<12, blk, 0, stream>>>(bq, bk, bv, bqkv);
    ln_kernel<true><<<ROWS, blk, 0, stream>>>(x, g1, be1, nx);
    gemm_bt<64, 128, 32, ushort><<<gQKV, blk, 0, stream>>>(nx, Wts, bqkv, nullptr, nullptr, nullptr, Qb, ROWS, 3072, Dc, 0, 1);
    vconv_kernel<<<cV, blk, 0, stream>>>(Vb, Vt);
    attn_kernel<<<dim3(1024), blk, 0, stream>>>(Qb, Kb, Vt, rel, ctx);
    gemm_bt<64, 128, 64, ushort><<<gD, blk, 0, stream>>>(ctx, Wts + (size_t)3 * 1024 * 1024, bo, x, nullptr, nullptr, x1, ROWS, Dc, Dc, 0, 0);
    ln_kernel<false><<<ROWS, blk, 0, stream>>>(x1, g2, be2, nx2);
    wconv_kernel<<<c1, blk, 0, stream>>>(w1, Wts, Dc, DFFc);
    gemm8_bt<ushort><<<gFF, blk8, 0, stream>>>(nx2, Wts, b1, hb, DFFc, Dc, 1, 0);
    wconv_kernel<<<c2, blk, 0, stream>>>(w2, Wts, DFFc, Dc);
    gemm_bt<64, 128, 64, ushort><<<gD, blk, 0, stream>>>(hb, Wts, b2, nullptr, nx2, nullptr, yb, ROWS, Dc, DFFc, 0, 0);
    ln_kernel<false><<<ROWS, blk, 0, stream>>>(yb, gf, bfp, ly);
    wconv_kernel<<<cD, blk, 0, stream>>>(w3, Wts, Dc, Dc);
    gemm_bt<64, 128, 64, float><<<gD, blk, 0, stream>>>(ly, Wts, b3, nullptr, x1, yb, out, ROWS, Dc, Dc, 0, 0);
}